// Round 17
// baseline (154.297 us; speedup 1.0000x reference)
//
#include <hip/hip_runtime.h>

// ---------------------------------------------------------------------------
// SelfAttention (B=4, S=2048, E=1024), fp32 in/out, bf16 MFMA internally.
// Round 17 = r16 with the rs_part indexing FIXED (32 partials/row: 8 bn x 4
// wc quadrants of 64 cols each; r16 shipped stride 8 = overrun -> wrong sums).
// gsco8 epilogue: plain partial-sum stores (no atomics). gout: one LDS
// reduction of the 32 partials per row after the K-loop (LDS is dead there),
// epilogue divides by lds_rs[row-gm0]; the 25% ones-MFMA overhead stays gone.
// Algebra (Q/K/V never materialized):
//   HT = (scale/ln2) * Wk^T Wq ; G = Wp Wv^T ; c1 = (scale/ln2)(bq.Wk);
//   cv = Wp.bv ; R = x.HT^T + c1 ; E = 2^(R.x^T) (+partial rowsums);
//   VWt = G.x^T + cv ; out = (E.VWt^T)/rowsum + bp
// Launches: prep1 -> prep2 -> gmid -> gsco8 -> gout.
// ---------------------------------------------------------------------------

typedef __bf16 bf16x8 __attribute__((ext_vector_type(8)));
typedef float  f32x4  __attribute__((ext_vector_type(4)));
typedef unsigned short u16x8 __attribute__((ext_vector_type(8)));

__device__ __forceinline__ float bf2f(unsigned short u) {
  return __uint_as_float(((unsigned int)u) << 16);
}
__device__ __forceinline__ unsigned short f2bf(float f) {
  unsigned int u = __float_as_uint(f);
  return (unsigned short)((u + 0x7fffu + ((u >> 16) & 1u)) >> 16);
}
__device__ __forceinline__ void gload16(const void* g, void* l) {
  __builtin_amdgcn_global_load_lds(
      (const __attribute__((address_space(1))) void*)g,
      (__attribute__((address_space(3))) void*)l, 16, 0, 0);
}

// ---------------------------------------------------------------------------
// gemm32_core: BM=256, BN=128, BK=32, double-buffered 48KB LDS (2 blocks/CU).
// EPI 4: bf16 + bias[row]; EPI 5: bf16 + bias[col]
// ---------------------------------------------------------------------------
template <int EPI>
__device__ __forceinline__ void gemm32_core(
    char* lds, int nwg, int base,
    const unsigned short* __restrict__ A, const unsigned short* __restrict__ B,
    void* __restrict__ C, const float* __restrict__ bias,
    int K, long long sA, long long sB, long long sC,
    int nbm, int nbn, int ldc) {
  char* ldsA = lds;            // 2 x 16KB
  char* ldsB = lds + 32768;    // 2 x 8KB

  int id = (int)blockIdx.x - base;
  id = (id & 7) * (nwg >> 3) + (id >> 3);
  const int nbmn = nbm * nbn;
  const int bz = id / nbmn;
  const int rem = id - bz * nbmn;
  const int bm = rem / nbn;          // bn-fastest
  const int bn = rem - bm * nbn;
  const int gm0 = bm * 256, gn0 = bn * 128;

  const unsigned short* Ag = A + (size_t)bz * sA;
  const unsigned short* Bg = B + (size_t)bz * sB;

  const int tid = threadIdx.x;
  const int w = tid >> 6, l = tid & 63;
  const int wr = w >> 1, wc = w & 1;     // 4M x 2N
  const int lr = l & 15;
  const int rchunk = ((l >> 4) ^ ((lr >> 1) & 3)) << 4;  // read slot byte

  const int srow = tid >> 2;                               // 0..127
  const int sbo  = (((tid & 3) ^ ((tid >> 3) & 3)) << 4);  // source chunk byte
  const int sdst = tid * 16;

#define STG32_A(bufsel, ktile)                                                 \
  do {                                                                         \
    char* _d = ldsA + (bufsel) * 16384 + sdst;                                 \
    const char* _s0 = (const char*)(Ag + (size_t)(gm0 + srow) * K) +           \
                      (size_t)(ktile) * 64 + sbo;                              \
    const char* _s1 = (const char*)(Ag + (size_t)(gm0 + 128 + srow) * K) +     \
                      (size_t)(ktile) * 64 + sbo;                              \
    gload16(_s0, _d);                                                          \
    gload16(_s1, _d + 8192);                                                   \
  } while (0)
#define STG32_B(bufsel, ktile)                                                 \
  do {                                                                         \
    const char* _s = (const char*)(Bg + (size_t)(gn0 + srow) * K) +            \
                     (size_t)(ktile) * 64 + sbo;                               \
    gload16(_s, ldsB + (bufsel) * 8192 + sdst);                                \
  } while (0)

#define RD32_A(dst, m)                                                         \
  dst = *(const bf16x8*)(Abuf + (wr * 64 + (m) * 16 + lr) * 64 + rchunk)
#define RD32_B(dst, n)                                                         \
  dst = *(const bf16x8*)(Bbuf + (wc * 64 + (n) * 16 + lr) * 64 + rchunk)

  f32x4 acc[4][4];
#pragma unroll
  for (int i = 0; i < 4; ++i)
#pragma unroll
    for (int j = 0; j < 4; ++j) acc[i][j] = (f32x4){0.f, 0.f, 0.f, 0.f};

  const int nt = K >> 5;

  STG32_A(0, 0); STG32_B(0, 0);
  asm volatile("s_waitcnt vmcnt(0)" ::: "memory");
  __builtin_amdgcn_s_barrier();

  for (int t = 0; t < nt; ++t) {
    const int cur = t & 1;
    char* Abuf = ldsA + cur * 16384;
    char* Bbuf = ldsB + cur * 8192;
    const bool pf = (t + 1 < nt);

    if (pf) { STG32_A(cur ^ 1, t + 1); STG32_B(cur ^ 1, t + 1); }

    bf16x8 av[4], bv[4];
#pragma unroll
    for (int m = 0; m < 4; ++m) RD32_A(av[m], m);
#pragma unroll
    for (int n = 0; n < 4; ++n) RD32_B(bv[n], n);
    asm volatile("s_waitcnt lgkmcnt(0)" ::: "memory");
    __builtin_amdgcn_sched_barrier(0);
    __builtin_amdgcn_s_setprio(1);
#pragma unroll
    for (int m = 0; m < 4; ++m)
#pragma unroll
      for (int n = 0; n < 4; ++n)
        acc[m][n] = __builtin_amdgcn_mfma_f32_16x16x32_bf16(av[m], bv[n],
                                                            acc[m][n], 0, 0, 0);
    __builtin_amdgcn_s_setprio(0);
    if (pf) { asm volatile("s_waitcnt vmcnt(0)" ::: "memory"); }
    __builtin_amdgcn_s_barrier();
  }

  const int cr = (l >> 4) * 4;
  const int cc = l & 15;
  unsigned short* Cp = (unsigned short*)C + (size_t)bz * sC;
#pragma unroll
  for (int m = 0; m < 4; ++m) {
    const int row = gm0 + wr * 64 + m * 16 + cr;
#pragma unroll
    for (int n = 0; n < 4; ++n) {
      const int col = gn0 + wc * 64 + n * 16 + cc;
      f32x4 a = acc[m][n];
#pragma unroll
      for (int j = 0; j < 4; ++j) {
        float v;
        if constexpr (EPI == 4) v = a[j] + bias[row + j];
        else                    v = a[j] + bias[col];   // EPI 5
        Cp[(size_t)(row + j) * ldc + col] = f2bf(v);
      }
    }
  }
#undef STG32_A
#undef STG32_B
#undef RD32_A
#undef RD32_B
}

// ---------------------------------------------------------------------------
// 256x128 engine (4-phase, BK=64, triple-buffer 144KB).
// EPI 1: bf16 * scale
// EPI 3: fp32 / rowsum + bias[col]; rowsum = LDS-reduced 32 partials/row
// ---------------------------------------------------------------------------
template <int EPI>
__device__ __forceinline__ void gemm_core(
    char* lds, int nwg, int base,
    const unsigned short* __restrict__ A, const unsigned short* __restrict__ B,
    void* __restrict__ C, const float* __restrict__ bias,
    const float* __restrict__ rspart,
    int K, long long sA, long long sB, long long sC,
    int nbm, int nbn, int ldc, float scale) {
  char* ldsA = lds;            // 3 x 32KB
  char* ldsB = lds + 98304;    // 3 x 16KB

  int id = (int)blockIdx.x - base;
  id = (id & 7) * (nwg >> 3) + (id >> 3);
  const int nbmn = nbm * nbn;
  const int bz = id / nbmn;
  const int rem = id - bz * nbmn;
  const int bm = rem / nbn;          // bn-fastest
  const int bn = rem - bm * nbn;
  const int gm0 = bm * 256, gn0 = bn * 128;

  const unsigned short* Ag = A + (size_t)bz * sA;
  const unsigned short* Bg = B + (size_t)bz * sB;

  const int tid = threadIdx.x;
  const int w = tid >> 6, l = tid & 63;
  const int wr = w >> 1, wc = w & 1;     // 4M x 2N
  const int lr = l & 15;
  const int lk16 = (l >> 4) * 16;
  const int swz = (lr & 7) << 4;

  const int srow = tid >> 3;
  const int sbo  = ((tid & 7) * 16) ^ ((srow & 7) << 4);
  const int sdst = tid * 16;

#define STG_A2(region, ktile, half)                                            \
  do {                                                                         \
    const char* _b =                                                           \
        (const char*)(Ag + (size_t)(gm0 + srow + (half) * 128) * K) +          \
        (size_t)(ktile) * 128 + sbo;                                           \
    const size_t _rk = (size_t)64 * K * 2;                                     \
    gload16(_b,       (region) + (half) * 16384 + sdst);                       \
    gload16(_b + _rk, (region) + (half) * 16384 + 8192 + sdst);                \
  } while (0)
#define STG_B(region, ktile)                                                   \
  do {                                                                         \
    const char* _b = (const char*)(Bg + (size_t)(gn0 + srow) * K) +            \
                     (size_t)(ktile) * 128 + sbo;                              \
    const size_t _rk = (size_t)64 * K * 2;                                     \
    gload16(_b,       (region) + sdst);                                        \
    gload16(_b + _rk, (region) + 8192 + sdst);                                 \
  } while (0)

#define RD_A(dst, m, kh)                                                       \
  dst = *(const bf16x8*)(Abuf + (wr * 64 + (m) * 16 + lr) * 128 +              \
                         ((lk16 + (kh) * 64) ^ swz))
#define RD_B(dst, n, kh)                                                       \
  dst = *(const bf16x8*)(Bbuf + (wc * 64 + (n) * 16 + lr) * 128 +              \
                         ((lk16 + (kh) * 64) ^ swz))

#define LGKM_PIN()                                          \
  asm volatile("s_waitcnt lgkmcnt(0)" ::: "memory");        \
  __builtin_amdgcn_sched_barrier(0)

#define MFMA8(mi0, mi1)                                                        \
  __builtin_amdgcn_s_setprio(1);                                               \
  _Pragma("unroll")                                                            \
  for (int n = 0; n < 4; ++n) {                                                \
    acc[mi0][n] = __builtin_amdgcn_mfma_f32_16x16x32_bf16(a0, bfr[n],          \
                                                          acc[mi0][n], 0,0,0); \
    acc[mi1][n] = __builtin_amdgcn_mfma_f32_16x16x32_bf16(a1, bfr[n],          \
                                                          acc[mi1][n], 0,0,0); \
  }                                                                            \
  __builtin_amdgcn_s_setprio(0)

  f32x4 acc[4][4];
#pragma unroll
  for (int i = 0; i < 4; ++i)
#pragma unroll
    for (int j = 0; j < 4; ++j) acc[i][j] = (f32x4){0.f, 0.f, 0.f, 0.f};

  const int nt = K >> 6;

  STG_B(ldsB, 0); STG_A2(ldsA, 0, 0); STG_A2(ldsA, 0, 1);
  if (nt > 1) {
    STG_B(ldsB + 16384, 1);
    STG_A2(ldsA + 32768, 1, 0); STG_A2(ldsA + 32768, 1, 1);
  }
  if (nt > 1) { asm volatile("s_waitcnt vmcnt(6)" ::: "memory"); }
  else        { asm volatile("s_waitcnt vmcnt(0)" ::: "memory"); }
  __builtin_amdgcn_s_barrier();

  int cur = 0;
  for (int t = 0; t < nt; ++t) {
    char* Abuf = ldsA + cur * 32768;
    char* Bbuf = ldsB + cur * 16384;
    const int nx2 = (cur + 2 >= 3) ? cur - 1 : cur + 2;
    const bool pf = (t + 2 < nt);

    bf16x8 a0, a1, bfr[4];
    // ---- P0: m0-1 x kh0 ----
    RD_A(a0, 0, 0); RD_A(a1, 1, 0);
#pragma unroll
    for (int n = 0; n < 4; ++n) RD_B(bfr[n], n, 0);
    if (pf) STG_B(ldsB + nx2 * 16384, t + 2);
    __builtin_amdgcn_s_barrier();
    LGKM_PIN();
    MFMA8(0, 1);
    __builtin_amdgcn_s_barrier();

    // ---- P1: m2-3 x kh0 ----
    RD_A(a0, 2, 0); RD_A(a1, 3, 0);
    if (pf) STG_A2(ldsA + nx2 * 32768, t + 2, 0);
    __builtin_amdgcn_s_barrier();
    LGKM_PIN();
    MFMA8(2, 3);
    __builtin_amdgcn_s_barrier();

    // ---- P2: m0-1 x kh1 ----
    RD_A(a0, 0, 1); RD_A(a1, 1, 1);
#pragma unroll
    for (int n = 0; n < 4; ++n) RD_B(bfr[n], n, 1);
    if (pf) STG_A2(ldsA + nx2 * 32768, t + 2, 1);
    __builtin_amdgcn_s_barrier();
    LGKM_PIN();
    MFMA8(0, 1);
    __builtin_amdgcn_s_barrier();

    // ---- P3: m2-3 x kh1 ----
    RD_A(a0, 2, 1); RD_A(a1, 3, 1);
    __builtin_amdgcn_s_barrier();
    LGKM_PIN();
    MFMA8(2, 3);
    if (pf)              { asm volatile("s_waitcnt vmcnt(6)" ::: "memory"); }
    else if (t + 1 < nt) { asm volatile("s_waitcnt vmcnt(0)" ::: "memory"); }
    __builtin_amdgcn_s_barrier();

    cur = (cur + 1 >= 3) ? 0 : cur + 1;
  }

  // EPI 3: reduce this block's 256 rowsums (32 partials each) into LDS.
  // LDS is dead after the loop's final barrier; reuse it as float[256].
  float* lds_rs = (float*)lds;
  if constexpr (EPI == 3) {
    if (tid < 256) {
      const float* rp = rspart + ((size_t)bz * 2048 + gm0 + tid) * 32;
      f32x4 s = *(const f32x4*)rp;
#pragma unroll
      for (int q = 1; q < 8; ++q) {
        f32x4 v = *(const f32x4*)(rp + q * 4);
        s[0] += v[0]; s[1] += v[1]; s[2] += v[2]; s[3] += v[3];
      }
      lds_rs[tid] = (s[0] + s[1]) + (s[2] + s[3]);
    }
    __syncthreads();
  }

  const int cr = (l >> 4) * 4;
  const int cc = l & 15;
#pragma unroll
  for (int m = 0; m < 4; ++m) {
    const int row = gm0 + wr * 64 + m * 16 + cr;
    if constexpr (EPI == 3) {
      f32x4 inv;
#pragma unroll
      for (int j = 0; j < 4; ++j)
        inv[j] = 1.0f / lds_rs[row - gm0 + j];
      float* Cp = (float*)C + (size_t)bz * sC;
#pragma unroll
      for (int n = 0; n < 4; ++n) {
        const int col = gn0 + wc * 64 + n * 16 + cc;
        const float b = bias[col];
        f32x4 a = acc[m][n];
#pragma unroll
        for (int j = 0; j < 4; ++j)
          Cp[(size_t)(row + j) * ldc + col] = a[j] * inv[j] + b;
      }
    } else {
      unsigned short* Cp = (unsigned short*)C + (size_t)bz * sC;
#pragma unroll
      for (int n = 0; n < 4; ++n) {
        const int col = gn0 + wc * 64 + n * 16 + cc;
        f32x4 a = acc[m][n];
#pragma unroll
        for (int j = 0; j < 4; ++j)
          Cp[(size_t)(row + j) * ldc + col] = f2bf(a[j] * scale);
      }
    }
  }
#undef STG_A2
#undef STG_B
#undef RD_A
#undef RD_B
#undef LGKM_PIN
#undef MFMA8
}

// ---------------------------------------------------------------------------
// prep1: [0,768) transpose-convert Wq/Wk/Wv (64x64 tiles);
//        [768,1280) Wp straight convert.
// ---------------------------------------------------------------------------
__global__ __launch_bounds__(256) void prep1(
    const float* __restrict__ wq, const float* __restrict__ wk,
    const float* __restrict__ wv, const float* __restrict__ wp,
    unsigned short* __restrict__ qt, unsigned short* __restrict__ kt,
    unsigned short* __restrict__ vt, unsigned short* __restrict__ wp_bf) {
  const int tid = threadIdx.x;
  if (blockIdx.x >= 768) {
    const int i = ((blockIdx.x - 768) * 256 + tid) * 8;
    f32x4 a = *(const f32x4*)(wp + i);
    f32x4 b = *(const f32x4*)(wp + i + 4);
    u16x8 o;
    o[0] = f2bf(a[0]); o[1] = f2bf(a[1]); o[2] = f2bf(a[2]); o[3] = f2bf(a[3]);
    o[4] = f2bf(b[0]); o[5] = f2bf(b[1]); o[6] = f2bf(b[2]); o[7] = f2bf(b[3]);
    *(u16x8*)(wp_bf + i) = o;
    return;
  }
  const float* in;
  unsigned short* out;
  int b = blockIdx.x;
  if (b < 256)      { in = wq; out = qt; }
  else if (b < 512) { in = wk; out = kt; b -= 256; }
  else              { in = wv; out = vt; b -= 512; }
  const int r0 = (b >> 4) * 64, c0 = (b & 15) * 64;
  __shared__ unsigned short t[64][72];
  const int rr = tid >> 4;
  const int cc4 = (tid & 15) * 4;
#pragma unroll
  for (int p = 0; p < 4; ++p) {
    const int r = rr + p * 16;
    f32x4 v = *(const f32x4*)(in + (size_t)(r0 + r) * 1024 + c0 + cc4);
    t[cc4 + 0][r] = f2bf(v[0]);
    t[cc4 + 1][r] = f2bf(v[1]);
    t[cc4 + 2][r] = f2bf(v[2]);
    t[cc4 + 3][r] = f2bf(v[3]);
  }
  __syncthreads();
  const int wr_ = tid >> 3;
  const int wc8 = (tid & 7) * 8;
#pragma unroll
  for (int p = 0; p < 2; ++p) {
    const int c = wr_ + p * 32;
    u16x8 o;
#pragma unroll
    for (int j = 0; j < 8; ++j) o[j] = t[c][wc8 + j];
    *(u16x8*)(out + (size_t)(c0 + c) * 1024 + r0 + wc8) = o;
  }
}

// ---------------------------------------------------------------------------
// prep2 (256 blocks x 512 thr):
//   [0,32)    HT = (scale/ln2)*WkT.WqT^T   (4-phase engine)
//   [32,64)   G  = Wp.WvT^T
//   [64,192)  convert x -> x_bf: 128 blocks, 16 vec8/thread, 4x4 unrolled
//   [192,224) c1: 32 blocks x 32 outputs, 16 f-groups
//   [224,256) cv: 32 blocks, wave per row
// ---------------------------------------------------------------------------
__global__ __launch_bounds__(512) void prep2(
    const unsigned short* __restrict__ WkT, const unsigned short* __restrict__ WqT,
    const unsigned short* __restrict__ Wp_bf, const unsigned short* __restrict__ WvT,
    unsigned short* __restrict__ HT, unsigned short* __restrict__ G,
    const float* __restrict__ x, unsigned short* __restrict__ x_bf,
    const float* __restrict__ bq, const float* __restrict__ Wk,
    const float* __restrict__ Wp, const float* __restrict__ bv,
    float* __restrict__ c1, float* __restrict__ cv, float scale) {
  __shared__ char lds[147456];
  const int bid = (int)blockIdx.x;
  const int tid = threadIdx.x;
  if (bid < 32) {
    gemm_core<1>(lds, 32, 0, WkT, WqT, HT, nullptr, nullptr,
                 1024, 0, 0, 0, 4, 8, 1024, scale);
  } else if (bid < 64) {
    gemm_core<1>(lds, 32, 32, Wp_bf, WvT, G, nullptr, nullptr,
                 1024, 0, 0, 0, 4, 8, 1024, 1.0f);
  } else if (bid < 192) {
    const int tg = (bid - 64) * 512 + tid;   // 0..65535
#pragma unroll
    for (int b = 0; b < 4; ++b) {
      f32x4 A[4], Bv[4];
#pragma unroll
      for (int k = 0; k < 4; ++k) {
        const int i = (tg + (b * 4 + k) * 65536) * 8;
        A[k]  = *(const f32x4*)(x + i);
        Bv[k] = *(const f32x4*)(x + i + 4);
      }
#pragma unroll
      for (int k = 0; k < 4; ++k) {
        const int i = (tg + (b * 4 + k) * 65536) * 8;
        u16x8 o;
        o[0] = f2bf(A[k][0]);  o[1] = f2bf(A[k][1]);
        o[2] = f2bf(A[k][2]);  o[3] = f2bf(A[k][3]);
        o[4] = f2bf(Bv[k][0]); o[5] = f2bf(Bv[k][1]);
        o[6] = f2bf(Bv[k][2]); o[7] = f2bf(Bv[k][3]);
        *(u16x8*)(x_bf + i) = o;
      }
    }
  } else if (bid < 224) {
    float* red = (float*)lds;              // 16 x 32 floats
    const int e_loc = tid & 31;
    const int fg = tid >> 5;               // 0..15
    const int e = (bid - 192) * 32 + e_loc;
    const float* wkcol = Wk + e;
    float acc = 0.f;
#pragma unroll 4
    for (int f = fg * 64; f < fg * 64 + 64; ++f)
      acc = fmaf(bq[f], wkcol[(size_t)f * 1024], acc);
    red[fg * 32 + e_loc] = acc;
    __syncthreads();
    if (fg == 0) {
      float s = 0.f;
#pragma unroll
      for (int g = 0; g < 16; ++g) s += red[g * 32 + e_loc];
      c1[e] = s * scale;
    }
  } else {
    const int l = tid & 63;
    for (int e = (bid - 224) * 8 + (tid >> 6); e < 1024; e += 256) {
      float acc = 0.f;
#pragma unroll
      for (int f = l; f < 1024; f += 64) acc += Wp[(size_t)e * 1024 + f] * bv[f];
#pragma unroll
      for (int i = 1; i < 64; i <<= 1) acc += __shfl_xor(acc, i, 64);
      if (l == 0) cv[e] = acc;
    }
  }
}

// gmid: [0,256) R = x.HT^T + c1 ; [256,512) VWt[b] = G.x[b]^T + cv
__global__ __launch_bounds__(512, 4) void gmid(
    const unsigned short* x, const unsigned short* HT, unsigned short* R,
    const float* c1, const unsigned short* G, unsigned short* VWt,
    const float* cv) {
  __shared__ char lds[49152];
  if (blockIdx.x < 256)
    gemm32_core<5>(lds, 256, 0, x, HT, R, c1,
                   1024, 0, 0, 0, 32, 8, 1024);
  else
    gemm32_core<4>(lds, 256, 256, G, x, VWt, cv,
                   1024, 0, 2097152, 2097152, 4, 16, 2048);
}

// gout: out = (E.VWt^T)/rowsum + bp  (rowsum = 32 partials from gsco8)
__global__ __launch_bounds__(512) void gout(
    const unsigned short* E, const unsigned short* VWt, float* out,
    const float* bp, const float* rs_part) {
  __shared__ char lds[147456];
  gemm_core<3>(lds, 256, 0, E, VWt, out, bp, rs_part,
               2048, 4194304, 2097152, 2097152, 8, 8, 1024, 0.f);
}

// ---------------------------------------------------------------------------
// gsco8: 8-phase 256x256 engine; E = 2^(R[b].x[b]^T); epilogue writes
// per-(bn,wc) partial row sums (64 cols each) to rs_part[bz][row][32].
// ---------------------------------------------------------------------------
__global__ __launch_bounds__(512) void gsco8(
    const unsigned short* __restrict__ A, const unsigned short* __restrict__ B,
    unsigned short* __restrict__ C, float* __restrict__ rs_part,
    int K, long long sA, long long sB, long long sC, int nbm, int nbn) {
  __shared__ char lds[131072];
  char* ldsA = lds;
  char* ldsB = lds + 65536;

  const int nwg = (int)gridDim.x;
  int id = (int)blockIdx.x;
  id = (id & 7) * (nwg >> 3) + (id >> 3);
  const int nbmn = nbm * nbn;
  const int bz = id / nbmn;
  const int rem = id - bz * nbmn;
  const int bm = rem / nbn;
  const int bn = rem - bm * nbn;
  const int gm0 = bm * 256, gn0 = bn * 256;

  const unsigned short* Ag = A + (size_t)bz * sA;
  const unsigned short* Bg = B + (size_t)bz * sB;

  const int tid = threadIdx.x;
  const int w = tid >> 6, l = tid & 63;
  const int wr = w >> 2, wc = w & 3;
  const int lr = l & 15;
  const int lk16 = (l >> 4) * 16;
  const int swz = (lr & 7) << 4;

  const int srow0 = (tid * 16) >> 7;
  const int srow1 = srow0 + 64;
  const int sbo   = ((tid * 16) & 127) ^ ((srow0 & 7) << 4);
  const int sdst0 = tid * 16;
  const int sdst1 = tid * 16 + 8192;

#define STAGE(gbase, grow0, region, ktile)                                     \
  do {                                                                         \
    const char* _s0 =                                                          \
        (const char*)((gbase) + (size_t)((grow0) + srow0) * K) +               \
        (ktile) * 128 + sbo;                                                   \
    const char* _s1 =                                                          \
        (const char*)((gbase) + (size_t)((grow0) + srow1) * K) +               \
        (ktile) * 128 + sbo;                                                   \
    gload16(_s0, (region) + sdst0);                                            \
    gload16(_s1, (region) + sdst1);                                            \
  } while (0)

#define RDA(dst, m, kh) \
  dst = *(const bf16x8*)(Areg + ((m) * 16 + lr) * 128 + ((lk16 + (kh) * 64) ^ swz))
#define RDB(dst, n, kh) \
  dst = *(const bf16x8*)(Breg + (((wc & 1) * 64 + (n) * 16 + lr) * 128) + ((lk16 + (kh) * 64) ^ swz))

  f32x4 acc[8][4];
#pragma unroll
  for (int i = 0; i < 8; ++i)
#pragma unroll
    for (int j = 0; j < 4; ++j) acc[i][j] = (f32x4){0.f, 0.f, 0.f, 0.f};

  bf16x8 af[4][2], bf_[4][2];

#define MM(mi, ai, n)                                                          \
  acc[mi][n] = __builtin_amdgcn_mfma_f32_16x16x32_bf16(af[ai][0], bf_[n][0],   \
                                                       acc[mi][n], 0, 0, 0);   \
  acc[mi][n] = __builtin_amdgcn_mfma_f32_16x16x32_bf16(af[ai][1], bf_[n][1],   \
                                                       acc[mi][n], 0, 0, 0)

#define LGKM_PIN()                                          \
  asm volatile("s_waitcnt lgkmcnt(0)" ::: "memory");        \
  __builtin_amdgcn_sched_barrier(0)

  const int nt = K >> 6;

  STAGE(Bg, gn0,       ldsB + 0,     0);
  STAGE(Bg, gn0 + 128, ldsB + 16384, 0);
  STAGE(Ag, gm0,       ldsA + 0,     0);
  STAGE(Ag, gm0 + 128, ldsA + 16384, 0);
  STAGE(Bg, gn0,       ldsB + 32768,         1);
  STAGE(Bg, gn0 + 128, ldsB + 32768 + 16384, 1);
  STAGE(Ag, gm0,       ldsA + 32768,         1);
  asm volatile("s_waitcnt vmcnt(6)" ::: "memory");
  __builtin_amdgcn_s_barrier();

  for (int t = 0; t < nt; ++t) {
    const int cur = t & 1;
    char* Areg  = ldsA + cur * 32768 + wr * 16384;
    char* Breg  = ldsB + cur * 32768 + (wc >> 1) * 16384;
    char* Anext = ldsA + (cur ^ 1) * 32768;
    char* Acur2 = ldsA + cur * 32768;
    char* Bcur2 = ldsB + cur * 32768;

#pragma unroll
    for (int m = 0; m < 4; ++m) { RDA(af[m][0], m, 0); RDA(af[m][1], m, 1); }
#pragma unroll
    for (int n = 0; n < 2; ++n) { RDB(bf_[n][0], n, 0); RDB(bf_[n][1], n, 1); }
    if (wc < 2) {
#pragma unroll
      for (int n = 2; n < 4; ++n) { RDB(bf_[n][0], n, 0); RDB(bf_[n][1], n, 1); }
    }
    if (t + 1 < nt) STAGE(Ag, gm0 + 128, Anext + 16384, t + 1);
    __builtin_amdgcn_s_barrier();
    LGKM_PIN();
    __builtin_amdgcn_s_setprio(1);
    MM(0, 0, 0); MM(0, 0, 1); MM(1, 1, 0); MM(1, 1, 1);
    MM(2, 2, 0); MM(2, 2, 1); MM(3, 3, 0); MM(3, 3, 1);
    __builtin_amdgcn_s_setprio(0);
    __builtin_amdgcn_s_barrier();

    if (wc >= 2) {
#pragma unroll
      for (int n = 2; n < 4; ++n) { RDB(bf_[n][0], n, 0); RDB(bf_[n][1], n, 1); }
    }
    if (t + 2 < nt) STAGE(Bg, gn0, Bcur2, t + 2);
    __builtin_amdgcn_s_barrier();
    LGKM_PIN();
    __builtin_amdgcn_s_setprio(1);
    MM(0, 0, 2); MM(0, 0, 3); MM(1, 1, 2); MM(1, 1, 3);
    MM(2, 2, 2); MM(2, 2, 3); MM(3, 3, 2); MM(3, 3, 3);
    __builtin_amdgcn_s_setprio(0);
    __builtin_amdgcn_s_barrier();

#pragma unroll
    for (int m = 0; m < 4; ++m) { RDA(af[m][0], m + 4, 0); RDA(af[m][1], m + 4, 1); }
    if (t + 2 < nt) STAGE(Bg, gn0 + 128, Bcur2 + 16384, t + 2);
    __builtin_amdgcn_s_barrier();
    LGKM_PIN();
    __builtin_amdgcn_s_setprio(1);
    MM(4, 0, 0); MM(4, 0, 1); MM(5, 1, 0); MM(5, 1, 1);
    MM(6, 2, 0); MM(6, 2, 1); MM(7, 3, 0); MM(7, 3, 1);
    __builtin_amdgcn_s_setprio(0);
    __builtin_amdgcn_s_barrier();

    if (t + 2 < nt) STAGE(Ag, gm0, Acur2, t + 2);
    __builtin_amdgcn_s_barrier();
    __builtin_amdgcn_s_setprio(1);
    MM(4, 0, 2); MM(4, 0, 3); MM(5, 1, 2); MM(5, 1, 3);
    MM(6, 2, 2); MM(6, 2, 3); MM(7, 3, 2); MM(7, 3, 3);
    __builtin_amdgcn_s_setprio(0);
    if (t + 2 < nt) {
      asm volatile("s_waitcnt vmcnt(6)" ::: "memory");
    } else {
      asm volatile("s_waitcnt vmcnt(0)" ::: "memory");
    }
    __builtin_amdgcn_s_barrier();
  }

  // epilogue: E = exp2(s') bf16; per-(bn,wc) 64-col partial row sums.
  // 16-lane reduce within each cr-group (lanes share the same 4 rows);
  // leader (l&15)==0 writes slot bn*4+wc of the row's 32-slot vector.
  const int cr = (l >> 4) * 4;
  const int cc = l & 15;
  unsigned short* Cp = C + (size_t)bz * sC;
#pragma unroll
  for (int m = 0; m < 8; ++m) {
    const int row = gm0 + wr * 128 + m * 16 + cr;
    float psum[4] = {0.f, 0.f, 0.f, 0.f};
#pragma unroll
    for (int n = 0; n < 4; ++n) {
      const int col = gn0 + wc * 64 + n * 16 + cc;
      f32x4 a = acc[m][n];
#pragma unroll
      for (int j = 0; j < 4; ++j) {
        const unsigned short us = f2bf(exp2f(a[j]));
        Cp[(size_t)(row + j) * 2048 + col] = us;
        psum[j] += bf2f(us);
      }
    }
#pragma unroll
    for (int j = 0; j < 4; ++j) {
#pragma unroll
      for (int i = 1; i < 16; i <<= 1) psum[j] += __shfl_xor(psum[j], i, 16);
      if ((l & 15) == 0)
        rs_part[((size_t)bz * 2048 + row + j) * 32 + (bn * 4 + wc)] = psum[j];
    }
  }
#undef STAGE
#undef RDA
#undef RDB
#undef MM
#undef LGKM_PIN
}

extern "C" void kernel_launch(void* const* d_in, const int* in_sizes, int n_in,
                              void* d_out, int out_size, void* d_ws, size_t ws_size,
                              hipStream_t stream) {
  const float* x  = (const float*)d_in[0];
  const float* Wq = (const float*)d_in[1];
  const float* bq = (const float*)d_in[2];
  const float* Wk = (const float*)d_in[3];
  const float* bk = (const float*)d_in[4];  (void)bk;  // cancels in softmax
  const float* Wv = (const float*)d_in[5];
  const float* bv = (const float*)d_in[6];
  const float* Wp = (const float*)d_in[7];
  const float* bp = (const float*)d_in[8];
  float* out = (float*)d_out;

  char* ws = (char*)d_ws;
  unsigned short* x_bf  = (unsigned short*)(ws);
  unsigned short* Wp_bf = (unsigned short*)(ws + (16ull << 20));
  unsigned short* WqT   = (unsigned short*)(ws + (18ull << 20));
  unsigned short* WkT   = (unsigned short*)(ws + (20ull << 20));
  unsigned short* WvT   = (unsigned short*)(ws + (22ull << 20));
  unsigned short* HT    = (unsigned short*)(ws + (24ull << 20));
  unsigned short* G     = (unsigned short*)(ws + (26ull << 20));
  float*          c1    = (float*)(ws + (28ull << 20));
  float*          cv    = (float*)(ws + (28ull << 20) + 65536);
  unsigned short* R     = (unsigned short*)(ws + (32ull << 20));
  unsigned short* VWt   = (unsigned short*)(ws + (48ull << 20));
  unsigned short* Em    = (unsigned short*)(ws + (64ull << 20));
  float*          rs_part = (float*)(ws + (96ull << 20));  // [4][2048][32] f32

  // scale/ln2: exp2(s') == exp(s); fold propagates linearly through R
  const float scale_ht = 0.022097086912079608f * 1.4426950408889634f;

  prep1<<<1280, 256, 0, stream>>>(Wq, Wk, Wv, Wp, WqT, WkT, WvT, Wp_bf);
  prep2<<<256, 512, 0, stream>>>(WkT, WqT, Wp_bf, WvT, HT, G,
                                 x, x_bf, bq, Wk, Wp, bv, c1, cv, scale_ht);
  gmid<<<512, 512, 0, stream>>>(x_bf, HT, R, c1, G, VWt, cv);
  gsco8<<<256, 512, 0, stream>>>(R, x_bf, Em, rs_part,
                                 1024, 2097152, 2097152, 4194304, 8, 8);
  gout<<<256, 512, 0, stream>>>(Em, VWt, out, bp, rs_part);
}

// Round 18
// 151.235 us; speedup vs baseline: 1.0202x; 1.0202x over previous
//
#include <hip/hip_runtime.h>

// ---------------------------------------------------------------------------
// SelfAttention (B=4, S=2048, E=1024), fp32 in/out, bf16 MFMA internally.
// Round 18 = exact revert to r15 (session best, 151.3 us). r17's partial-sum
// experiment proved the shfl-reduce epilogue costs ~9us regardless of
// atomics; r15's ones-MFMA rowsum in gout (+4.5us) is the cheapest of the
// three measured rowsum designs. Holding r15 as final.
// Algebra (Q/K/V never materialized):
//   HT = (scale/ln2) * Wk^T Wq ; G = Wp Wv^T ; c1 = (scale/ln2)(bq.Wk);
//   cv = Wp.bv ; R = x.HT^T + c1 ; E = 2^(R.x^T) ;
//   VWt = G.x^T + cv ; out = (E.VWt^T)/rowsum(E) + bp
//   (rowsum computed inside gout via MFMA against all-ones B fragment)
// Launches: prep1 -> prep2 -> gmid -> gsco8 -> gout.
// ---------------------------------------------------------------------------

typedef __bf16 bf16x8 __attribute__((ext_vector_type(8)));
typedef float  f32x4  __attribute__((ext_vector_type(4)));
typedef unsigned short u16x8 __attribute__((ext_vector_type(8)));

__device__ __forceinline__ float bf2f(unsigned short u) {
  return __uint_as_float(((unsigned int)u) << 16);
}
__device__ __forceinline__ unsigned short f2bf(float f) {
  unsigned int u = __float_as_uint(f);
  return (unsigned short)((u + 0x7fffu + ((u >> 16) & 1u)) >> 16);
}
__device__ __forceinline__ void gload16(const void* g, void* l) {
  __builtin_amdgcn_global_load_lds(
      (const __attribute__((address_space(1))) void*)g,
      (__attribute__((address_space(3))) void*)l, 16, 0, 0);
}

// ---------------------------------------------------------------------------
// gemm32_core: BM=256, BN=128, BK=32, double-buffered 48KB LDS (2 blocks/CU).
// EPI 4: bf16 + bias[row]; EPI 5: bf16 + bias[col]
// ---------------------------------------------------------------------------
template <int EPI>
__device__ __forceinline__ void gemm32_core(
    char* lds, int nwg, int base,
    const unsigned short* __restrict__ A, const unsigned short* __restrict__ B,
    void* __restrict__ C, const float* __restrict__ bias,
    int K, long long sA, long long sB, long long sC,
    int nbm, int nbn, int ldc) {
  char* ldsA = lds;            // 2 x 16KB
  char* ldsB = lds + 32768;    // 2 x 8KB

  int id = (int)blockIdx.x - base;
  id = (id & 7) * (nwg >> 3) + (id >> 3);
  const int nbmn = nbm * nbn;
  const int bz = id / nbmn;
  const int rem = id - bz * nbmn;
  const int bm = rem / nbn;          // bn-fastest
  const int bn = rem - bm * nbn;
  const int gm0 = bm * 256, gn0 = bn * 128;

  const unsigned short* Ag = A + (size_t)bz * sA;
  const unsigned short* Bg = B + (size_t)bz * sB;

  const int tid = threadIdx.x;
  const int w = tid >> 6, l = tid & 63;
  const int wr = w >> 1, wc = w & 1;     // 4M x 2N
  const int lr = l & 15;
  const int rchunk = ((l >> 4) ^ ((lr >> 1) & 3)) << 4;  // read slot byte

  const int srow = tid >> 2;                               // 0..127
  const int sbo  = (((tid & 3) ^ ((tid >> 3) & 3)) << 4);  // source chunk byte
  const int sdst = tid * 16;

#define STG32_A(bufsel, ktile)                                                 \
  do {                                                                         \
    char* _d = ldsA + (bufsel) * 16384 + sdst;                                 \
    const char* _s0 = (const char*)(Ag + (size_t)(gm0 + srow) * K) +           \
                      (size_t)(ktile) * 64 + sbo;                              \
    const char* _s1 = (const char*)(Ag + (size_t)(gm0 + 128 + srow) * K) +     \
                      (size_t)(ktile) * 64 + sbo;                              \
    gload16(_s0, _d);                                                          \
    gload16(_s1, _d + 8192);                                                   \
  } while (0)
#define STG32_B(bufsel, ktile)                                                 \
  do {                                                                         \
    const char* _s = (const char*)(Bg + (size_t)(gn0 + srow) * K) +            \
                     (size_t)(ktile) * 64 + sbo;                               \
    gload16(_s, ldsB + (bufsel) * 8192 + sdst);                                \
  } while (0)

#define RD32_A(dst, m)                                                         \
  dst = *(const bf16x8*)(Abuf + (wr * 64 + (m) * 16 + lr) * 64 + rchunk)
#define RD32_B(dst, n)                                                         \
  dst = *(const bf16x8*)(Bbuf + (wc * 64 + (n) * 16 + lr) * 64 + rchunk)

  f32x4 acc[4][4];
#pragma unroll
  for (int i = 0; i < 4; ++i)
#pragma unroll
    for (int j = 0; j < 4; ++j) acc[i][j] = (f32x4){0.f, 0.f, 0.f, 0.f};

  const int nt = K >> 5;

  STG32_A(0, 0); STG32_B(0, 0);
  asm volatile("s_waitcnt vmcnt(0)" ::: "memory");
  __builtin_amdgcn_s_barrier();

  for (int t = 0; t < nt; ++t) {
    const int cur = t & 1;
    char* Abuf = ldsA + cur * 16384;
    char* Bbuf = ldsB + cur * 8192;
    const bool pf = (t + 1 < nt);

    if (pf) { STG32_A(cur ^ 1, t + 1); STG32_B(cur ^ 1, t + 1); }

    bf16x8 av[4], bv[4];
#pragma unroll
    for (int m = 0; m < 4; ++m) RD32_A(av[m], m);
#pragma unroll
    for (int n = 0; n < 4; ++n) RD32_B(bv[n], n);
    asm volatile("s_waitcnt lgkmcnt(0)" ::: "memory");
    __builtin_amdgcn_sched_barrier(0);
    __builtin_amdgcn_s_setprio(1);
#pragma unroll
    for (int m = 0; m < 4; ++m)
#pragma unroll
      for (int n = 0; n < 4; ++n)
        acc[m][n] = __builtin_amdgcn_mfma_f32_16x16x32_bf16(av[m], bv[n],
                                                            acc[m][n], 0, 0, 0);
    __builtin_amdgcn_s_setprio(0);
    if (pf) { asm volatile("s_waitcnt vmcnt(0)" ::: "memory"); }
    __builtin_amdgcn_s_barrier();
  }

  const int cr = (l >> 4) * 4;
  const int cc = l & 15;
  unsigned short* Cp = (unsigned short*)C + (size_t)bz * sC;
#pragma unroll
  for (int m = 0; m < 4; ++m) {
    const int row = gm0 + wr * 64 + m * 16 + cr;
#pragma unroll
    for (int n = 0; n < 4; ++n) {
      const int col = gn0 + wc * 64 + n * 16 + cc;
      f32x4 a = acc[m][n];
#pragma unroll
      for (int j = 0; j < 4; ++j) {
        float v;
        if constexpr (EPI == 4) v = a[j] + bias[row + j];
        else                    v = a[j] + bias[col];   // EPI 5
        Cp[(size_t)(row + j) * ldc + col] = f2bf(v);
      }
    }
  }
#undef STG32_A
#undef STG32_B
#undef RD32_A
#undef RD32_B
}

// ---------------------------------------------------------------------------
// 256x128 engine (4-phase, BK=64, triple-buffer 144KB).
// EPI 1: bf16 * scale
// EPI 3: fp32 * inv(local rowsum via ones-MFMA) + bias[col]  (gout)
// ---------------------------------------------------------------------------
template <int EPI>
__device__ __forceinline__ void gemm_core(
    char* lds, int nwg, int base,
    const unsigned short* __restrict__ A, const unsigned short* __restrict__ B,
    void* __restrict__ C, const float* __restrict__ bias,
    int K, long long sA, long long sB, long long sC,
    int nbm, int nbn, int ldc, float scale) {
  char* ldsA = lds;            // 3 x 32KB
  char* ldsB = lds + 98304;    // 3 x 16KB

  int id = (int)blockIdx.x - base;
  id = (id & 7) * (nwg >> 3) + (id >> 3);
  const int nbmn = nbm * nbn;
  const int bz = id / nbmn;
  const int rem = id - bz * nbmn;
  const int bm = rem / nbn;          // bn-fastest
  const int bn = rem - bm * nbn;
  const int gm0 = bm * 256, gn0 = bn * 128;

  const unsigned short* Ag = A + (size_t)bz * sA;
  const unsigned short* Bg = B + (size_t)bz * sB;

  const int tid = threadIdx.x;
  const int w = tid >> 6, l = tid & 63;
  const int wr = w >> 1, wc = w & 1;     // 4M x 2N
  const int lr = l & 15;
  const int lk16 = (l >> 4) * 16;
  const int swz = (lr & 7) << 4;

  const int srow = tid >> 3;
  const int sbo  = ((tid & 7) * 16) ^ ((srow & 7) << 4);
  const int sdst = tid * 16;

#define STG_A2(region, ktile, half)                                            \
  do {                                                                         \
    const char* _b =                                                           \
        (const char*)(Ag + (size_t)(gm0 + srow + (half) * 128) * K) +          \
        (size_t)(ktile) * 128 + sbo;                                           \
    const size_t _rk = (size_t)64 * K * 2;                                     \
    gload16(_b,       (region) + (half) * 16384 + sdst);                       \
    gload16(_b + _rk, (region) + (half) * 16384 + 8192 + sdst);                \
  } while (0)
#define STG_B(region, ktile)                                                   \
  do {                                                                         \
    const char* _b = (const char*)(Bg + (size_t)(gn0 + srow) * K) +            \
                     (size_t)(ktile) * 128 + sbo;                              \
    const size_t _rk = (size_t)64 * K * 2;                                     \
    gload16(_b,       (region) + sdst);                                        \
    gload16(_b + _rk, (region) + 8192 + sdst);                                 \
  } while (0)

#define RD_A(dst, m, kh)                                                       \
  dst = *(const bf16x8*)(Abuf + (wr * 64 + (m) * 16 + lr) * 128 +              \
                         ((lk16 + (kh) * 64) ^ swz))
#define RD_B(dst, n, kh)                                                       \
  dst = *(const bf16x8*)(Bbuf + (wc * 64 + (n) * 16 + lr) * 128 +              \
                         ((lk16 + (kh) * 64) ^ swz))

#define LGKM_PIN()                                          \
  asm volatile("s_waitcnt lgkmcnt(0)" ::: "memory");        \
  __builtin_amdgcn_sched_barrier(0)

#define MFMA8(mi0, mi1)                                                        \
  __builtin_amdgcn_s_setprio(1);                                               \
  _Pragma("unroll")                                                            \
  for (int n = 0; n < 4; ++n) {                                                \
    acc[mi0][n] = __builtin_amdgcn_mfma_f32_16x16x32_bf16(a0, bfr[n],          \
                                                          acc[mi0][n], 0,0,0); \
    acc[mi1][n] = __builtin_amdgcn_mfma_f32_16x16x32_bf16(a1, bfr[n],          \
                                                          acc[mi1][n], 0,0,0); \
  }                                                                            \
  __builtin_amdgcn_s_setprio(0)

#define RSUM(mi0, mi1)                                                         \
  if constexpr (EPI == 3) {                                                    \
    acc_rs[mi0] = __builtin_amdgcn_mfma_f32_16x16x32_bf16(a0, onesB,           \
                                                          acc_rs[mi0], 0,0,0); \
    acc_rs[mi1] = __builtin_amdgcn_mfma_f32_16x16x32_bf16(a1, onesB,           \
                                                          acc_rs[mi1], 0,0,0); \
  }

  f32x4 acc[4][4];
#pragma unroll
  for (int i = 0; i < 4; ++i)
#pragma unroll
    for (int j = 0; j < 4; ++j) acc[i][j] = (f32x4){0.f, 0.f, 0.f, 0.f};

  f32x4 acc_rs[4];
  bf16x8 onesB;
  if constexpr (EPI == 3) {
    u16x8 ou;
#pragma unroll
    for (int j = 0; j < 8; ++j) ou[j] = 0x3F80;  // bf16 1.0
    onesB = *(bf16x8*)&ou;
#pragma unroll
    for (int i = 0; i < 4; ++i) acc_rs[i] = (f32x4){0.f, 0.f, 0.f, 0.f};
  }

  const int nt = K >> 6;

  STG_B(ldsB, 0); STG_A2(ldsA, 0, 0); STG_A2(ldsA, 0, 1);
  if (nt > 1) {
    STG_B(ldsB + 16384, 1);
    STG_A2(ldsA + 32768, 1, 0); STG_A2(ldsA + 32768, 1, 1);
  }
  if (nt > 1) { asm volatile("s_waitcnt vmcnt(6)" ::: "memory"); }
  else        { asm volatile("s_waitcnt vmcnt(0)" ::: "memory"); }
  __builtin_amdgcn_s_barrier();

  int cur = 0;
  for (int t = 0; t < nt; ++t) {
    char* Abuf = ldsA + cur * 32768;
    char* Bbuf = ldsB + cur * 16384;
    const int nx2 = (cur + 2 >= 3) ? cur - 1 : cur + 2;
    const bool pf = (t + 2 < nt);

    bf16x8 a0, a1, bfr[4];
    // ---- P0: m0-1 x kh0 ----
    RD_A(a0, 0, 0); RD_A(a1, 1, 0);
#pragma unroll
    for (int n = 0; n < 4; ++n) RD_B(bfr[n], n, 0);
    if (pf) STG_B(ldsB + nx2 * 16384, t + 2);
    __builtin_amdgcn_s_barrier();
    LGKM_PIN();
    MFMA8(0, 1);
    RSUM(0, 1)
    __builtin_amdgcn_s_barrier();

    // ---- P1: m2-3 x kh0 ----
    RD_A(a0, 2, 0); RD_A(a1, 3, 0);
    if (pf) STG_A2(ldsA + nx2 * 32768, t + 2, 0);
    __builtin_amdgcn_s_barrier();
    LGKM_PIN();
    MFMA8(2, 3);
    RSUM(2, 3)
    __builtin_amdgcn_s_barrier();

    // ---- P2: m0-1 x kh1 ----
    RD_A(a0, 0, 1); RD_A(a1, 1, 1);
#pragma unroll
    for (int n = 0; n < 4; ++n) RD_B(bfr[n], n, 1);
    if (pf) STG_A2(ldsA + nx2 * 32768, t + 2, 1);
    __builtin_amdgcn_s_barrier();
    LGKM_PIN();
    MFMA8(0, 1);
    RSUM(0, 1)
    __builtin_amdgcn_s_barrier();

    // ---- P3: m2-3 x kh1 ----
    RD_A(a0, 2, 1); RD_A(a1, 3, 1);
    __builtin_amdgcn_s_barrier();
    LGKM_PIN();
    MFMA8(2, 3);
    RSUM(2, 3)
    if (pf)              { asm volatile("s_waitcnt vmcnt(6)" ::: "memory"); }
    else if (t + 1 < nt) { asm volatile("s_waitcnt vmcnt(0)" ::: "memory"); }
    __builtin_amdgcn_s_barrier();

    cur = (cur + 1 >= 3) ? 0 : cur + 1;
  }

  const int cr = (l >> 4) * 4;
  const int cc = l & 15;
#pragma unroll
  for (int m = 0; m < 4; ++m) {
    const int row = gm0 + wr * 64 + m * 16 + cr;
    if constexpr (EPI == 3) {
      f32x4 inv;
#pragma unroll
      for (int j = 0; j < 4; ++j) inv[j] = 1.0f / acc_rs[m][j];
      float* Cp = (float*)C + (size_t)bz * sC;
#pragma unroll
      for (int n = 0; n < 4; ++n) {
        const int col = gn0 + wc * 64 + n * 16 + cc;
        const float b = bias[col];
        f32x4 a = acc[m][n];
#pragma unroll
        for (int j = 0; j < 4; ++j)
          Cp[(size_t)(row + j) * ldc + col] = a[j] * inv[j] + b;
      }
    } else {
      unsigned short* Cp = (unsigned short*)C + (size_t)bz * sC;
#pragma unroll
      for (int n = 0; n < 4; ++n) {
        const int col = gn0 + wc * 64 + n * 16 + cc;
        f32x4 a = acc[m][n];
#pragma unroll
        for (int j = 0; j < 4; ++j)
          Cp[(size_t)(row + j) * ldc + col] = f2bf(a[j] * scale);
      }
    }
  }
#undef STG_A2
#undef STG_B
#undef RD_A
#undef RD_B
#undef LGKM_PIN
#undef MFMA8
#undef RSUM
}

// ---------------------------------------------------------------------------
// prep1: [0,768) transpose-convert Wq/Wk/Wv (64x64 tiles);
//        [768,1280) Wp straight convert.
// ---------------------------------------------------------------------------
__global__ __launch_bounds__(256) void prep1(
    const float* __restrict__ wq, const float* __restrict__ wk,
    const float* __restrict__ wv, const float* __restrict__ wp,
    unsigned short* __restrict__ qt, unsigned short* __restrict__ kt,
    unsigned short* __restrict__ vt, unsigned short* __restrict__ wp_bf) {
  const int tid = threadIdx.x;
  if (blockIdx.x >= 768) {
    const int i = ((blockIdx.x - 768) * 256 + tid) * 8;
    f32x4 a = *(const f32x4*)(wp + i);
    f32x4 b = *(const f32x4*)(wp + i + 4);
    u16x8 o;
    o[0] = f2bf(a[0]); o[1] = f2bf(a[1]); o[2] = f2bf(a[2]); o[3] = f2bf(a[3]);
    o[4] = f2bf(b[0]); o[5] = f2bf(b[1]); o[6] = f2bf(b[2]); o[7] = f2bf(b[3]);
    *(u16x8*)(wp_bf + i) = o;
    return;
  }
  const float* in;
  unsigned short* out;
  int b = blockIdx.x;
  if (b < 256)      { in = wq; out = qt; }
  else if (b < 512) { in = wk; out = kt; b -= 256; }
  else              { in = wv; out = vt; b -= 512; }
  const int r0 = (b >> 4) * 64, c0 = (b & 15) * 64;
  __shared__ unsigned short t[64][72];
  const int rr = tid >> 4;
  const int cc4 = (tid & 15) * 4;
#pragma unroll
  for (int p = 0; p < 4; ++p) {
    const int r = rr + p * 16;
    f32x4 v = *(const f32x4*)(in + (size_t)(r0 + r) * 1024 + c0 + cc4);
    t[cc4 + 0][r] = f2bf(v[0]);
    t[cc4 + 1][r] = f2bf(v[1]);
    t[cc4 + 2][r] = f2bf(v[2]);
    t[cc4 + 3][r] = f2bf(v[3]);
  }
  __syncthreads();
  const int wr_ = tid >> 3;
  const int wc8 = (tid & 7) * 8;
#pragma unroll
  for (int p = 0; p < 2; ++p) {
    const int c = wr_ + p * 32;
    u16x8 o;
#pragma unroll
    for (int j = 0; j < 8; ++j) o[j] = t[c][wc8 + j];
    *(u16x8*)(out + (size_t)(c0 + c) * 1024 + r0 + wc8) = o;
  }
}

// ---------------------------------------------------------------------------
// prep2 (256 blocks x 512 thr):
//   [0,32)    HT = (scale/ln2)*WkT.WqT^T   (4-phase engine)
//   [32,64)   G  = Wp.WvT^T
//   [64,192)  convert x -> x_bf: 128 blocks, 16 vec8/thread, 4x4 unrolled
//   [192,224) c1: 32 blocks x 32 outputs, 16 f-groups
//   [224,256) cv: 32 blocks, wave per row
// ---------------------------------------------------------------------------
__global__ __launch_bounds__(512) void prep2(
    const unsigned short* __restrict__ WkT, const unsigned short* __restrict__ WqT,
    const unsigned short* __restrict__ Wp_bf, const unsigned short* __restrict__ WvT,
    unsigned short* __restrict__ HT, unsigned short* __restrict__ G,
    const float* __restrict__ x, unsigned short* __restrict__ x_bf,
    const float* __restrict__ bq, const float* __restrict__ Wk,
    const float* __restrict__ Wp, const float* __restrict__ bv,
    float* __restrict__ c1, float* __restrict__ cv, float scale) {
  __shared__ char lds[147456];
  const int bid = (int)blockIdx.x;
  const int tid = threadIdx.x;
  if (bid < 32) {
    gemm_core<1>(lds, 32, 0, WkT, WqT, HT, nullptr,
                 1024, 0, 0, 0, 4, 8, 1024, scale);
  } else if (bid < 64) {
    gemm_core<1>(lds, 32, 32, Wp_bf, WvT, G, nullptr,
                 1024, 0, 0, 0, 4, 8, 1024, 1.0f);
  } else if (bid < 192) {
    const int tg = (bid - 64) * 512 + tid;   // 0..65535
#pragma unroll
    for (int b = 0; b < 4; ++b) {
      f32x4 A[4], Bv[4];
#pragma unroll
      for (int k = 0; k < 4; ++k) {
        const int i = (tg + (b * 4 + k) * 65536) * 8;
        A[k]  = *(const f32x4*)(x + i);
        Bv[k] = *(const f32x4*)(x + i + 4);
      }
#pragma unroll
      for (int k = 0; k < 4; ++k) {
        const int i = (tg + (b * 4 + k) * 65536) * 8;
        u16x8 o;
        o[0] = f2bf(A[k][0]);  o[1] = f2bf(A[k][1]);
        o[2] = f2bf(A[k][2]);  o[3] = f2bf(A[k][3]);
        o[4] = f2bf(Bv[k][0]); o[5] = f2bf(Bv[k][1]);
        o[6] = f2bf(Bv[k][2]); o[7] = f2bf(Bv[k][3]);
        *(u16x8*)(x_bf + i) = o;
      }
    }
  } else if (bid < 224) {
    float* red = (float*)lds;              // 16 x 32 floats
    const int e_loc = tid & 31;
    const int fg = tid >> 5;               // 0..15
    const int e = (bid - 192) * 32 + e_loc;
    const float* wkcol = Wk + e;
    float acc = 0.f;
#pragma unroll 4
    for (int f = fg * 64; f < fg * 64 + 64; ++f)
      acc = fmaf(bq[f], wkcol[(size_t)f * 1024], acc);
    red[fg * 32 + e_loc] = acc;
    __syncthreads();
    if (fg == 0) {
      float s = 0.f;
#pragma unroll
      for (int g = 0; g < 16; ++g) s += red[g * 32 + e_loc];
      c1[e] = s * scale;
    }
  } else {
    const int l = tid & 63;
    for (int e = (bid - 224) * 8 + (tid >> 6); e < 1024; e += 256) {
      float acc = 0.f;
#pragma unroll
      for (int f = l; f < 1024; f += 64) acc += Wp[(size_t)e * 1024 + f] * bv[f];
#pragma unroll
      for (int i = 1; i < 64; i <<= 1) acc += __shfl_xor(acc, i, 64);
      if (l == 0) cv[e] = acc;
    }
  }
}

// gmid: [0,256) R = x.HT^T + c1 ; [256,512) VWt[b] = G.x[b]^T + cv
__global__ __launch_bounds__(512, 4) void gmid(
    const unsigned short* x, const unsigned short* HT, unsigned short* R,
    const float* c1, const unsigned short* G, unsigned short* VWt,
    const float* cv) {
  __shared__ char lds[49152];
  if (blockIdx.x < 256)
    gemm32_core<5>(lds, 256, 0, x, HT, R, c1,
                   1024, 0, 0, 0, 32, 8, 1024);
  else
    gemm32_core<4>(lds, 256, 256, G, x, VWt, cv,
                   1024, 0, 2097152, 2097152, 4, 16, 2048);
}

// gout: out = (E.VWt^T)/rowsum_local + bp
__global__ __launch_bounds__(512) void gout(
    const unsigned short* E, const unsigned short* VWt, float* out,
    const float* bp) {
  __shared__ char lds[147456];
  gemm_core<3>(lds, 256, 0, E, VWt, out, bp,
               2048, 4194304, 2097152, 2097152, 8, 8, 1024, 0.f);
}

// ---------------------------------------------------------------------------
// gsco8: 8-phase 256x256 engine; E = 2^(R[b] . x[b]^T) — pure exp2+store.
// ---------------------------------------------------------------------------
__global__ __launch_bounds__(512) void gsco8(
    const unsigned short* __restrict__ A, const unsigned short* __restrict__ B,
    unsigned short* __restrict__ C,
    int K, long long sA, long long sB, long long sC, int nbm, int nbn) {
  __shared__ char lds[131072];
  char* ldsA = lds;
  char* ldsB = lds + 65536;

  const int nwg = (int)gridDim.x;
  int id = (int)blockIdx.x;
  id = (id & 7) * (nwg >> 3) + (id >> 3);
  const int nbmn = nbm * nbn;
  const int bz = id / nbmn;
  const int rem = id - bz * nbmn;
  const int bm = rem / nbn;
  const int bn = rem - bm * nbn;
  const int gm0 = bm * 256, gn0 = bn * 256;

  const unsigned short* Ag = A + (size_t)bz * sA;
  const unsigned short* Bg = B + (size_t)bz * sB;

  const int tid = threadIdx.x;
  const int w = tid >> 6, l = tid & 63;
  const int wr = w >> 2, wc = w & 3;
  const int lr = l & 15;
  const int lk16 = (l >> 4) * 16;
  const int swz = (lr & 7) << 4;

  const int srow0 = (tid * 16) >> 7;
  const int srow1 = srow0 + 64;
  const int sbo   = ((tid * 16) & 127) ^ ((srow0 & 7) << 4);
  const int sdst0 = tid * 16;
  const int sdst1 = tid * 16 + 8192;

#define STAGE(gbase, grow0, region, ktile)                                     \
  do {                                                                         \
    const char* _s0 =                                                          \
        (const char*)((gbase) + (size_t)((grow0) + srow0) * K) +               \
        (ktile) * 128 + sbo;                                                   \
    const char* _s1 =                                                          \
        (const char*)((gbase) + (size_t)((grow0) + srow1) * K) +               \
        (ktile) * 128 + sbo;                                                   \
    gload16(_s0, (region) + sdst0);                                            \
    gload16(_s1, (region) + sdst1);                                            \
  } while (0)

#define RDA(dst, m, kh) \
  dst = *(const bf16x8*)(Areg + ((m) * 16 + lr) * 128 + ((lk16 + (kh) * 64) ^ swz))
#define RDB(dst, n, kh) \
  dst = *(const bf16x8*)(Breg + (((wc & 1) * 64 + (n) * 16 + lr) * 128) + ((lk16 + (kh) * 64) ^ swz))

  f32x4 acc[8][4];
#pragma unroll
  for (int i = 0; i < 8; ++i)
#pragma unroll
    for (int j = 0; j < 4; ++j) acc[i][j] = (f32x4){0.f, 0.f, 0.f, 0.f};

  bf16x8 af[4][2], bf_[4][2];

#define MM(mi, ai, n)                                                          \
  acc[mi][n] = __builtin_amdgcn_mfma_f32_16x16x32_bf16(af[ai][0], bf_[n][0],   \
                                                       acc[mi][n], 0, 0, 0);   \
  acc[mi][n] = __builtin_amdgcn_mfma_f32_16x16x32_bf16(af[ai][1], bf_[n][1],   \
                                                       acc[mi][n], 0, 0, 0)

#define LGKM_PIN()                                          \
  asm volatile("s_waitcnt lgkmcnt(0)" ::: "memory");        \
  __builtin_amdgcn_sched_barrier(0)

  const int nt = K >> 6;

  STAGE(Bg, gn0,       ldsB + 0,     0);
  STAGE(Bg, gn0 + 128, ldsB + 16384, 0);
  STAGE(Ag, gm0,       ldsA + 0,     0);
  STAGE(Ag, gm0 + 128, ldsA + 16384, 0);
  STAGE(Bg, gn0,       ldsB + 32768,         1);
  STAGE(Bg, gn0 + 128, ldsB + 32768 + 16384, 1);
  STAGE(Ag, gm0,       ldsA + 32768,         1);
  asm volatile("s_waitcnt vmcnt(6)" ::: "memory");
  __builtin_amdgcn_s_barrier();

  for (int t = 0; t < nt; ++t) {
    const int cur = t & 1;
    char* Areg  = ldsA + cur * 32768 + wr * 16384;
    char* Breg  = ldsB + cur * 32768 + (wc >> 1) * 16384;
    char* Anext = ldsA + (cur ^ 1) * 32768;
    char* Acur2 = ldsA + cur * 32768;
    char* Bcur2 = ldsB + cur * 32768;

#pragma unroll
    for (int m = 0; m < 4; ++m) { RDA(af[m][0], m, 0); RDA(af[m][1], m, 1); }
#pragma unroll
    for (int n = 0; n < 2; ++n) { RDB(bf_[n][0], n, 0); RDB(bf_[n][1], n, 1); }
    if (wc < 2) {
#pragma unroll
      for (int n = 2; n < 4; ++n) { RDB(bf_[n][0], n, 0); RDB(bf_[n][1], n, 1); }
    }
    if (t + 1 < nt) STAGE(Ag, gm0 + 128, Anext + 16384, t + 1);
    __builtin_amdgcn_s_barrier();
    LGKM_PIN();
    __builtin_amdgcn_s_setprio(1);
    MM(0, 0, 0); MM(0, 0, 1); MM(1, 1, 0); MM(1, 1, 1);
    MM(2, 2, 0); MM(2, 2, 1); MM(3, 3, 0); MM(3, 3, 1);
    __builtin_amdgcn_s_setprio(0);
    __builtin_amdgcn_s_barrier();

    if (wc >= 2) {
#pragma unroll
      for (int n = 2; n < 4; ++n) { RDB(bf_[n][0], n, 0); RDB(bf_[n][1], n, 1); }
    }
    if (t + 2 < nt) STAGE(Bg, gn0, Bcur2, t + 2);
    __builtin_amdgcn_s_barrier();
    LGKM_PIN();
    __builtin_amdgcn_s_setprio(1);
    MM(0, 0, 2); MM(0, 0, 3); MM(1, 1, 2); MM(1, 1, 3);
    MM(2, 2, 2); MM(2, 2, 3); MM(3, 3, 2); MM(3, 3, 3);
    __builtin_amdgcn_s_setprio(0);
    __builtin_amdgcn_s_barrier();

#pragma unroll
    for (int m = 0; m < 4; ++m) { RDA(af[m][0], m + 4, 0); RDA(af[m][1], m + 4, 1); }
    if (t + 2 < nt) STAGE(Bg, gn0 + 128, Bcur2 + 16384, t + 2);
    __builtin_amdgcn_s_barrier();
    LGKM_PIN();
    __builtin_amdgcn_s_setprio(1);
    MM(4, 0, 0); MM(4, 0, 1); MM(5, 1, 0); MM(5, 1, 1);
    MM(6, 2, 0); MM(6, 2, 1); MM(7, 3, 0); MM(7, 3, 1);
    __builtin_amdgcn_s_setprio(0);
    __builtin_amdgcn_s_barrier();

    if (t + 2 < nt) STAGE(Ag, gm0, Acur2, t + 2);
    __builtin_amdgcn_s_barrier();
    __builtin_amdgcn_s_setprio(1);
    MM(4, 0, 2); MM(4, 0, 3); MM(5, 1, 2); MM(5, 1, 3);
    MM(6, 2, 2); MM(6, 2, 3); MM(7, 3, 2); MM(7, 3, 3);
    __builtin_amdgcn_s_setprio(0);
    if (t + 2 < nt) {
      asm volatile("s_waitcnt vmcnt(6)" ::: "memory");
    } else {
      asm volatile("s_waitcnt vmcnt(0)" ::: "memory");
    }
    __builtin_amdgcn_s_barrier();
  }

  // epilogue: E = exp2(s') bf16 — pure convert+store
  const int cr = (l >> 4) * 4;
  const int cc = l & 15;
  unsigned short* Cp = C + (size_t)bz * sC;
#pragma unroll
  for (int m = 0; m < 8; ++m) {
    const int row = gm0 + wr * 128 + m * 16 + cr;
#pragma unroll
    for (int n = 0; n < 4; ++n) {
      const int col = gn0 + wc * 64 + n * 16 + cc;
      f32x4 a = acc[m][n];
#pragma unroll
      for (int j = 0; j < 4; ++j)
        Cp[(size_t)(row + j) * 2048 + col] = f2bf(exp2f(a[j]));
    }
  }
#undef STAGE
#undef RDA
#undef RDB
#undef MM
#undef LGKM_PIN
}

extern "C" void kernel_launch(void* const* d_in, const int* in_sizes, int n_in,
                              void* d_out, int out_size, void* d_ws, size_t ws_size,
                              hipStream_t stream) {
  const float* x  = (const float*)d_in[0];
  const float* Wq = (const float*)d_in[1];
  const float* bq = (const float*)d_in[2];
  const float* Wk = (const float*)d_in[3];
  const float* bk = (const float*)d_in[4];  (void)bk;  // cancels in softmax
  const float* Wv = (const float*)d_in[5];
  const float* bv = (const float*)d_in[6];
  const float* Wp = (const float*)d_in[7];
  const float* bp = (const float*)d_in[8];
  float* out = (float*)d_out;

  char* ws = (char*)d_ws;
  unsigned short* x_bf  = (unsigned short*)(ws);
  unsigned short* Wp_bf = (unsigned short*)(ws + (16ull << 20));
  unsigned short* WqT   = (unsigned short*)(ws + (18ull << 20));
  unsigned short* WkT   = (unsigned short*)(ws + (20ull << 20));
  unsigned short* WvT   = (unsigned short*)(ws + (22ull << 20));
  unsigned short* HT    = (unsigned short*)(ws + (24ull << 20));
  unsigned short* G     = (unsigned short*)(ws + (26ull << 20));
  float*          c1    = (float*)(ws + (28ull << 20));
  float*          cv    = (float*)(ws + (28ull << 20) + 65536);
  unsigned short* R     = (unsigned short*)(ws + (32ull << 20));
  unsigned short* VWt   = (unsigned short*)(ws + (48ull << 20));
  unsigned short* Em    = (unsigned short*)(ws + (64ull << 20));

  // scale/ln2: exp2(s') == exp(s); fold propagates linearly through R
  const float scale_ht = 0.022097086912079608f * 1.4426950408889634f;

  prep1<<<1280, 256, 0, stream>>>(Wq, Wk, Wv, Wp, WqT, WkT, WvT, Wp_bf);
  prep2<<<256, 512, 0, stream>>>(WkT, WqT, Wp_bf, WvT, HT, G,
                                 x, x_bf, bq, Wk, Wp, bv, c1, cv, scale_ht);
  gmid<<<512, 512, 0, stream>>>(x_bf, HT, R, c1, G, VWt, cv);
  gsco8<<<256, 512, 0, stream>>>(R, x_bf, Em,
                                 1024, 2097152, 2097152, 4194304, 8, 8);
  gout<<<256, 512, 0, stream>>>(Em, VWt, out, bp);
}

// Round 19
// 151.175 us; speedup vs baseline: 1.0207x; 1.0004x over previous
//
#include <hip/hip_runtime.h>

// ---------------------------------------------------------------------------
// SelfAttention (B=4, S=2048, E=1024), fp32 in/out, bf16 MFMA internally.
// Round 19 = r18 (confirmed best, 151.2us) + gsco8 epilogue uses raw
// v_exp_f32 (__builtin_amdgcn_exp2f) instead of guarded exp2f — args bounded
// |s'|<~3.2, result bf16-rounded, so the guard sequence is pure overhead.
// Algebra (Q/K/V never materialized):
//   HT = (scale/ln2) * Wk^T Wq ; G = Wp Wv^T ; c1 = (scale/ln2)(bq.Wk);
//   cv = Wp.bv ; R = x.HT^T + c1 ; E = 2^(R.x^T) ;
//   VWt = G.x^T + cv ; out = (E.VWt^T)/rowsum(E) + bp
//   (rowsum computed inside gout via MFMA against all-ones B fragment)
// Launches: prep1 -> prep2 -> gmid -> gsco8 -> gout.
// ---------------------------------------------------------------------------

typedef __bf16 bf16x8 __attribute__((ext_vector_type(8)));
typedef float  f32x4  __attribute__((ext_vector_type(4)));
typedef unsigned short u16x8 __attribute__((ext_vector_type(8)));

__device__ __forceinline__ float bf2f(unsigned short u) {
  return __uint_as_float(((unsigned int)u) << 16);
}
__device__ __forceinline__ unsigned short f2bf(float f) {
  unsigned int u = __float_as_uint(f);
  return (unsigned short)((u + 0x7fffu + ((u >> 16) & 1u)) >> 16);
}
__device__ __forceinline__ void gload16(const void* g, void* l) {
  __builtin_amdgcn_global_load_lds(
      (const __attribute__((address_space(1))) void*)g,
      (__attribute__((address_space(3))) void*)l, 16, 0, 0);
}

// ---------------------------------------------------------------------------
// gemm32_core: BM=256, BN=128, BK=32, double-buffered 48KB LDS (2 blocks/CU).
// EPI 4: bf16 + bias[row]; EPI 5: bf16 + bias[col]
// ---------------------------------------------------------------------------
template <int EPI>
__device__ __forceinline__ void gemm32_core(
    char* lds, int nwg, int base,
    const unsigned short* __restrict__ A, const unsigned short* __restrict__ B,
    void* __restrict__ C, const float* __restrict__ bias,
    int K, long long sA, long long sB, long long sC,
    int nbm, int nbn, int ldc) {
  char* ldsA = lds;            // 2 x 16KB
  char* ldsB = lds + 32768;    // 2 x 8KB

  int id = (int)blockIdx.x - base;
  id = (id & 7) * (nwg >> 3) + (id >> 3);
  const int nbmn = nbm * nbn;
  const int bz = id / nbmn;
  const int rem = id - bz * nbmn;
  const int bm = rem / nbn;          // bn-fastest
  const int bn = rem - bm * nbn;
  const int gm0 = bm * 256, gn0 = bn * 128;

  const unsigned short* Ag = A + (size_t)bz * sA;
  const unsigned short* Bg = B + (size_t)bz * sB;

  const int tid = threadIdx.x;
  const int w = tid >> 6, l = tid & 63;
  const int wr = w >> 1, wc = w & 1;     // 4M x 2N
  const int lr = l & 15;
  const int rchunk = ((l >> 4) ^ ((lr >> 1) & 3)) << 4;  // read slot byte

  const int srow = tid >> 2;                               // 0..127
  const int sbo  = (((tid & 3) ^ ((tid >> 3) & 3)) << 4);  // source chunk byte
  const int sdst = tid * 16;

#define STG32_A(bufsel, ktile)                                                 \
  do {                                                                         \
    char* _d = ldsA + (bufsel) * 16384 + sdst;                                 \
    const char* _s0 = (const char*)(Ag + (size_t)(gm0 + srow) * K) +           \
                      (size_t)(ktile) * 64 + sbo;                              \
    const char* _s1 = (const char*)(Ag + (size_t)(gm0 + 128 + srow) * K) +     \
                      (size_t)(ktile) * 64 + sbo;                              \
    gload16(_s0, _d);                                                          \
    gload16(_s1, _d + 8192);                                                   \
  } while (0)
#define STG32_B(bufsel, ktile)                                                 \
  do {                                                                         \
    const char* _s = (const char*)(Bg + (size_t)(gn0 + srow) * K) +            \
                     (size_t)(ktile) * 64 + sbo;                               \
    gload16(_s, ldsB + (bufsel) * 8192 + sdst);                                \
  } while (0)

#define RD32_A(dst, m)                                                         \
  dst = *(const bf16x8*)(Abuf + (wr * 64 + (m) * 16 + lr) * 64 + rchunk)
#define RD32_B(dst, n)                                                         \
  dst = *(const bf16x8*)(Bbuf + (wc * 64 + (n) * 16 + lr) * 64 + rchunk)

  f32x4 acc[4][4];
#pragma unroll
  for (int i = 0; i < 4; ++i)
#pragma unroll
    for (int j = 0; j < 4; ++j) acc[i][j] = (f32x4){0.f, 0.f, 0.f, 0.f};

  const int nt = K >> 5;

  STG32_A(0, 0); STG32_B(0, 0);
  asm volatile("s_waitcnt vmcnt(0)" ::: "memory");
  __builtin_amdgcn_s_barrier();

  for (int t = 0; t < nt; ++t) {
    const int cur = t & 1;
    char* Abuf = ldsA + cur * 16384;
    char* Bbuf = ldsB + cur * 8192;
    const bool pf = (t + 1 < nt);

    if (pf) { STG32_A(cur ^ 1, t + 1); STG32_B(cur ^ 1, t + 1); }

    bf16x8 av[4], bv[4];
#pragma unroll
    for (int m = 0; m < 4; ++m) RD32_A(av[m], m);
#pragma unroll
    for (int n = 0; n < 4; ++n) RD32_B(bv[n], n);
    asm volatile("s_waitcnt lgkmcnt(0)" ::: "memory");
    __builtin_amdgcn_sched_barrier(0);
    __builtin_amdgcn_s_setprio(1);
#pragma unroll
    for (int m = 0; m < 4; ++m)
#pragma unroll
      for (int n = 0; n < 4; ++n)
        acc[m][n] = __builtin_amdgcn_mfma_f32_16x16x32_bf16(av[m], bv[n],
                                                            acc[m][n], 0, 0, 0);
    __builtin_amdgcn_s_setprio(0);
    if (pf) { asm volatile("s_waitcnt vmcnt(0)" ::: "memory"); }
    __builtin_amdgcn_s_barrier();
  }

  const int cr = (l >> 4) * 4;
  const int cc = l & 15;
  unsigned short* Cp = (unsigned short*)C + (size_t)bz * sC;
#pragma unroll
  for (int m = 0; m < 4; ++m) {
    const int row = gm0 + wr * 64 + m * 16 + cr;
#pragma unroll
    for (int n = 0; n < 4; ++n) {
      const int col = gn0 + wc * 64 + n * 16 + cc;
      f32x4 a = acc[m][n];
#pragma unroll
      for (int j = 0; j < 4; ++j) {
        float v;
        if constexpr (EPI == 4) v = a[j] + bias[row + j];
        else                    v = a[j] + bias[col];   // EPI 5
        Cp[(size_t)(row + j) * ldc + col] = f2bf(v);
      }
    }
  }
#undef STG32_A
#undef STG32_B
#undef RD32_A
#undef RD32_B
}

// ---------------------------------------------------------------------------
// 256x128 engine (4-phase, BK=64, triple-buffer 144KB).
// EPI 1: bf16 * scale
// EPI 3: fp32 * inv(local rowsum via ones-MFMA) + bias[col]  (gout)
// ---------------------------------------------------------------------------
template <int EPI>
__device__ __forceinline__ void gemm_core(
    char* lds, int nwg, int base,
    const unsigned short* __restrict__ A, const unsigned short* __restrict__ B,
    void* __restrict__ C, const float* __restrict__ bias,
    int K, long long sA, long long sB, long long sC,
    int nbm, int nbn, int ldc, float scale) {
  char* ldsA = lds;            // 3 x 32KB
  char* ldsB = lds + 98304;    // 3 x 16KB

  int id = (int)blockIdx.x - base;
  id = (id & 7) * (nwg >> 3) + (id >> 3);
  const int nbmn = nbm * nbn;
  const int bz = id / nbmn;
  const int rem = id - bz * nbmn;
  const int bm = rem / nbn;          // bn-fastest
  const int bn = rem - bm * nbn;
  const int gm0 = bm * 256, gn0 = bn * 128;

  const unsigned short* Ag = A + (size_t)bz * sA;
  const unsigned short* Bg = B + (size_t)bz * sB;

  const int tid = threadIdx.x;
  const int w = tid >> 6, l = tid & 63;
  const int wr = w >> 1, wc = w & 1;     // 4M x 2N
  const int lr = l & 15;
  const int lk16 = (l >> 4) * 16;
  const int swz = (lr & 7) << 4;

  const int srow = tid >> 3;
  const int sbo  = ((tid & 7) * 16) ^ ((srow & 7) << 4);
  const int sdst = tid * 16;

#define STG_A2(region, ktile, half)                                            \
  do {                                                                         \
    const char* _b =                                                           \
        (const char*)(Ag + (size_t)(gm0 + srow + (half) * 128) * K) +          \
        (size_t)(ktile) * 128 + sbo;                                           \
    const size_t _rk = (size_t)64 * K * 2;                                     \
    gload16(_b,       (region) + (half) * 16384 + sdst);                       \
    gload16(_b + _rk, (region) + (half) * 16384 + 8192 + sdst);                \
  } while (0)
#define STG_B(region, ktile)                                                   \
  do {                                                                         \
    const char* _b = (const char*)(Bg + (size_t)(gn0 + srow) * K) +            \
                     (size_t)(ktile) * 128 + sbo;                              \
    const size_t _rk = (size_t)64 * K * 2;                                     \
    gload16(_b,       (region) + sdst);                                        \
    gload16(_b + _rk, (region) + 8192 + sdst);                                 \
  } while (0)

#define RD_A(dst, m, kh)                                                       \
  dst = *(const bf16x8*)(Abuf + (wr * 64 + (m) * 16 + lr) * 128 +              \
                         ((lk16 + (kh) * 64) ^ swz))
#define RD_B(dst, n, kh)                                                       \
  dst = *(const bf16x8*)(Bbuf + (wc * 64 + (n) * 16 + lr) * 128 +              \
                         ((lk16 + (kh) * 64) ^ swz))

#define LGKM_PIN()                                          \
  asm volatile("s_waitcnt lgkmcnt(0)" ::: "memory");        \
  __builtin_amdgcn_sched_barrier(0)

#define MFMA8(mi0, mi1)                                                        \
  __builtin_amdgcn_s_setprio(1);                                               \
  _Pragma("unroll")                                                            \
  for (int n = 0; n < 4; ++n) {                                                \
    acc[mi0][n] = __builtin_amdgcn_mfma_f32_16x16x32_bf16(a0, bfr[n],          \
                                                          acc[mi0][n], 0,0,0); \
    acc[mi1][n] = __builtin_amdgcn_mfma_f32_16x16x32_bf16(a1, bfr[n],          \
                                                          acc[mi1][n], 0,0,0); \
  }                                                                            \
  __builtin_amdgcn_s_setprio(0)

#define RSUM(mi0, mi1)                                                         \
  if constexpr (EPI == 3) {                                                    \
    acc_rs[mi0] = __builtin_amdgcn_mfma_f32_16x16x32_bf16(a0, onesB,           \
                                                          acc_rs[mi0], 0,0,0); \
    acc_rs[mi1] = __builtin_amdgcn_mfma_f32_16x16x32_bf16(a1, onesB,           \
                                                          acc_rs[mi1], 0,0,0); \
  }

  f32x4 acc[4][4];
#pragma unroll
  for (int i = 0; i < 4; ++i)
#pragma unroll
    for (int j = 0; j < 4; ++j) acc[i][j] = (f32x4){0.f, 0.f, 0.f, 0.f};

  f32x4 acc_rs[4];
  bf16x8 onesB;
  if constexpr (EPI == 3) {
    u16x8 ou;
#pragma unroll
    for (int j = 0; j < 8; ++j) ou[j] = 0x3F80;  // bf16 1.0
    onesB = *(bf16x8*)&ou;
#pragma unroll
    for (int i = 0; i < 4; ++i) acc_rs[i] = (f32x4){0.f, 0.f, 0.f, 0.f};
  }

  const int nt = K >> 6;

  STG_B(ldsB, 0); STG_A2(ldsA, 0, 0); STG_A2(ldsA, 0, 1);
  if (nt > 1) {
    STG_B(ldsB + 16384, 1);
    STG_A2(ldsA + 32768, 1, 0); STG_A2(ldsA + 32768, 1, 1);
  }
  if (nt > 1) { asm volatile("s_waitcnt vmcnt(6)" ::: "memory"); }
  else        { asm volatile("s_waitcnt vmcnt(0)" ::: "memory"); }
  __builtin_amdgcn_s_barrier();

  int cur = 0;
  for (int t = 0; t < nt; ++t) {
    char* Abuf = ldsA + cur * 32768;
    char* Bbuf = ldsB + cur * 16384;
    const int nx2 = (cur + 2 >= 3) ? cur - 1 : cur + 2;
    const bool pf = (t + 2 < nt);

    bf16x8 a0, a1, bfr[4];
    // ---- P0: m0-1 x kh0 ----
    RD_A(a0, 0, 0); RD_A(a1, 1, 0);
#pragma unroll
    for (int n = 0; n < 4; ++n) RD_B(bfr[n], n, 0);
    if (pf) STG_B(ldsB + nx2 * 16384, t + 2);
    __builtin_amdgcn_s_barrier();
    LGKM_PIN();
    MFMA8(0, 1);
    RSUM(0, 1)
    __builtin_amdgcn_s_barrier();

    // ---- P1: m2-3 x kh0 ----
    RD_A(a0, 2, 0); RD_A(a1, 3, 0);
    if (pf) STG_A2(ldsA + nx2 * 32768, t + 2, 0);
    __builtin_amdgcn_s_barrier();
    LGKM_PIN();
    MFMA8(2, 3);
    RSUM(2, 3)
    __builtin_amdgcn_s_barrier();

    // ---- P2: m0-1 x kh1 ----
    RD_A(a0, 0, 1); RD_A(a1, 1, 1);
#pragma unroll
    for (int n = 0; n < 4; ++n) RD_B(bfr[n], n, 1);
    if (pf) STG_A2(ldsA + nx2 * 32768, t + 2, 1);
    __builtin_amdgcn_s_barrier();
    LGKM_PIN();
    MFMA8(0, 1);
    RSUM(0, 1)
    __builtin_amdgcn_s_barrier();

    // ---- P3: m2-3 x kh1 ----
    RD_A(a0, 2, 1); RD_A(a1, 3, 1);
    __builtin_amdgcn_s_barrier();
    LGKM_PIN();
    MFMA8(2, 3);
    RSUM(2, 3)
    if (pf)              { asm volatile("s_waitcnt vmcnt(6)" ::: "memory"); }
    else if (t + 1 < nt) { asm volatile("s_waitcnt vmcnt(0)" ::: "memory"); }
    __builtin_amdgcn_s_barrier();

    cur = (cur + 1 >= 3) ? 0 : cur + 1;
  }

  const int cr = (l >> 4) * 4;
  const int cc = l & 15;
#pragma unroll
  for (int m = 0; m < 4; ++m) {
    const int row = gm0 + wr * 64 + m * 16 + cr;
    if constexpr (EPI == 3) {
      f32x4 inv;
#pragma unroll
      for (int j = 0; j < 4; ++j) inv[j] = 1.0f / acc_rs[m][j];
      float* Cp = (float*)C + (size_t)bz * sC;
#pragma unroll
      for (int n = 0; n < 4; ++n) {
        const int col = gn0 + wc * 64 + n * 16 + cc;
        const float b = bias[col];
        f32x4 a = acc[m][n];
#pragma unroll
        for (int j = 0; j < 4; ++j)
          Cp[(size_t)(row + j) * ldc + col] = a[j] * inv[j] + b;
      }
    } else {
      unsigned short* Cp = (unsigned short*)C + (size_t)bz * sC;
#pragma unroll
      for (int n = 0; n < 4; ++n) {
        const int col = gn0 + wc * 64 + n * 16 + cc;
        f32x4 a = acc[m][n];
#pragma unroll
        for (int j = 0; j < 4; ++j)
          Cp[(size_t)(row + j) * ldc + col] = f2bf(a[j] * scale);
      }
    }
  }
#undef STG_A2
#undef STG_B
#undef RD_A
#undef RD_B
#undef LGKM_PIN
#undef MFMA8
#undef RSUM
}

// ---------------------------------------------------------------------------
// prep1: [0,768) transpose-convert Wq/Wk/Wv (64x64 tiles);
//        [768,1280) Wp straight convert.
// ---------------------------------------------------------------------------
__global__ __launch_bounds__(256) void prep1(
    const float* __restrict__ wq, const float* __restrict__ wk,
    const float* __restrict__ wv, const float* __restrict__ wp,
    unsigned short* __restrict__ qt, unsigned short* __restrict__ kt,
    unsigned short* __restrict__ vt, unsigned short* __restrict__ wp_bf) {
  const int tid = threadIdx.x;
  if (blockIdx.x >= 768) {
    const int i = ((blockIdx.x - 768) * 256 + tid) * 8;
    f32x4 a = *(const f32x4*)(wp + i);
    f32x4 b = *(const f32x4*)(wp + i + 4);
    u16x8 o;
    o[0] = f2bf(a[0]); o[1] = f2bf(a[1]); o[2] = f2bf(a[2]); o[3] = f2bf(a[3]);
    o[4] = f2bf(b[0]); o[5] = f2bf(b[1]); o[6] = f2bf(b[2]); o[7] = f2bf(b[3]);
    *(u16x8*)(wp_bf + i) = o;
    return;
  }
  const float* in;
  unsigned short* out;
  int b = blockIdx.x;
  if (b < 256)      { in = wq; out = qt; }
  else if (b < 512) { in = wk; out = kt; b -= 256; }
  else              { in = wv; out = vt; b -= 512; }
  const int r0 = (b >> 4) * 64, c0 = (b & 15) * 64;
  __shared__ unsigned short t[64][72];
  const int rr = tid >> 4;
  const int cc4 = (tid & 15) * 4;
#pragma unroll
  for (int p = 0; p < 4; ++p) {
    const int r = rr + p * 16;
    f32x4 v = *(const f32x4*)(in + (size_t)(r0 + r) * 1024 + c0 + cc4);
    t[cc4 + 0][r] = f2bf(v[0]);
    t[cc4 + 1][r] = f2bf(v[1]);
    t[cc4 + 2][r] = f2bf(v[2]);
    t[cc4 + 3][r] = f2bf(v[3]);
  }
  __syncthreads();
  const int wr_ = tid >> 3;
  const int wc8 = (tid & 7) * 8;
#pragma unroll
  for (int p = 0; p < 2; ++p) {
    const int c = wr_ + p * 32;
    u16x8 o;
#pragma unroll
    for (int j = 0; j < 8; ++j) o[j] = t[c][wc8 + j];
    *(u16x8*)(out + (size_t)(c0 + c) * 1024 + r0 + wc8) = o;
  }
}

// ---------------------------------------------------------------------------
// prep2 (256 blocks x 512 thr):
//   [0,32)    HT = (scale/ln2)*WkT.WqT^T   (4-phase engine)
//   [32,64)   G  = Wp.WvT^T
//   [64,192)  convert x -> x_bf: 128 blocks, 16 vec8/thread, 4x4 unrolled
//   [192,224) c1: 32 blocks x 32 outputs, 16 f-groups
//   [224,256) cv: 32 blocks, wave per row
// ---------------------------------------------------------------------------
__global__ __launch_bounds__(512) void prep2(
    const unsigned short* __restrict__ WkT, const unsigned short* __restrict__ WqT,
    const unsigned short* __restrict__ Wp_bf, const unsigned short* __restrict__ WvT,
    unsigned short* __restrict__ HT, unsigned short* __restrict__ G,
    const float* __restrict__ x, unsigned short* __restrict__ x_bf,
    const float* __restrict__ bq, const float* __restrict__ Wk,
    const float* __restrict__ Wp, const float* __restrict__ bv,
    float* __restrict__ c1, float* __restrict__ cv, float scale) {
  __shared__ char lds[147456];
  const int bid = (int)blockIdx.x;
  const int tid = threadIdx.x;
  if (bid < 32) {
    gemm_core<1>(lds, 32, 0, WkT, WqT, HT, nullptr,
                 1024, 0, 0, 0, 4, 8, 1024, scale);
  } else if (bid < 64) {
    gemm_core<1>(lds, 32, 32, Wp_bf, WvT, G, nullptr,
                 1024, 0, 0, 0, 4, 8, 1024, 1.0f);
  } else if (bid < 192) {
    const int tg = (bid - 64) * 512 + tid;   // 0..65535
#pragma unroll
    for (int b = 0; b < 4; ++b) {
      f32x4 A[4], Bv[4];
#pragma unroll
      for (int k = 0; k < 4; ++k) {
        const int i = (tg + (b * 4 + k) * 65536) * 8;
        A[k]  = *(const f32x4*)(x + i);
        Bv[k] = *(const f32x4*)(x + i + 4);
      }
#pragma unroll
      for (int k = 0; k < 4; ++k) {
        const int i = (tg + (b * 4 + k) * 65536) * 8;
        u16x8 o;
        o[0] = f2bf(A[k][0]);  o[1] = f2bf(A[k][1]);
        o[2] = f2bf(A[k][2]);  o[3] = f2bf(A[k][3]);
        o[4] = f2bf(Bv[k][0]); o[5] = f2bf(Bv[k][1]);
        o[6] = f2bf(Bv[k][2]); o[7] = f2bf(Bv[k][3]);
        *(u16x8*)(x_bf + i) = o;
      }
    }
  } else if (bid < 224) {
    float* red = (float*)lds;              // 16 x 32 floats
    const int e_loc = tid & 31;
    const int fg = tid >> 5;               // 0..15
    const int e = (bid - 192) * 32 + e_loc;
    const float* wkcol = Wk + e;
    float acc = 0.f;
#pragma unroll 4
    for (int f = fg * 64; f < fg * 64 + 64; ++f)
      acc = fmaf(bq[f], wkcol[(size_t)f * 1024], acc);
    red[fg * 32 + e_loc] = acc;
    __syncthreads();
    if (fg == 0) {
      float s = 0.f;
#pragma unroll
      for (int g = 0; g < 16; ++g) s += red[g * 32 + e_loc];
      c1[e] = s * scale;
    }
  } else {
    const int l = tid & 63;
    for (int e = (bid - 224) * 8 + (tid >> 6); e < 1024; e += 256) {
      float acc = 0.f;
#pragma unroll
      for (int f = l; f < 1024; f += 64) acc += Wp[(size_t)e * 1024 + f] * bv[f];
#pragma unroll
      for (int i = 1; i < 64; i <<= 1) acc += __shfl_xor(acc, i, 64);
      if (l == 0) cv[e] = acc;
    }
  }
}

// gmid: [0,256) R = x.HT^T + c1 ; [256,512) VWt[b] = G.x[b]^T + cv
__global__ __launch_bounds__(512, 4) void gmid(
    const unsigned short* x, const unsigned short* HT, unsigned short* R,
    const float* c1, const unsigned short* G, unsigned short* VWt,
    const float* cv) {
  __shared__ char lds[49152];
  if (blockIdx.x < 256)
    gemm32_core<5>(lds, 256, 0, x, HT, R, c1,
                   1024, 0, 0, 0, 32, 8, 1024);
  else
    gemm32_core<4>(lds, 256, 256, G, x, VWt, cv,
                   1024, 0, 2097152, 2097152, 4, 16, 2048);
}

// gout: out = (E.VWt^T)/rowsum_local + bp
__global__ __launch_bounds__(512) void gout(
    const unsigned short* E, const unsigned short* VWt, float* out,
    const float* bp) {
  __shared__ char lds[147456];
  gemm_core<3>(lds, 256, 0, E, VWt, out, bp,
               2048, 4194304, 2097152, 2097152, 8, 8, 1024, 0.f);
}

// ---------------------------------------------------------------------------
// gsco8: 8-phase 256x256 engine; E = 2^(R[b] . x[b]^T) — pure exp2+store,
// raw v_exp_f32 (args bounded, result bf16-rounded).
// ---------------------------------------------------------------------------
__global__ __launch_bounds__(512) void gsco8(
    const unsigned short* __restrict__ A, const unsigned short* __restrict__ B,
    unsigned short* __restrict__ C,
    int K, long long sA, long long sB, long long sC, int nbm, int nbn) {
  __shared__ char lds[131072];
  char* ldsA = lds;
  char* ldsB = lds + 65536;

  const int nwg = (int)gridDim.x;
  int id = (int)blockIdx.x;
  id = (id & 7) * (nwg >> 3) + (id >> 3);
  const int nbmn = nbm * nbn;
  const int bz = id / nbmn;
  const int rem = id - bz * nbmn;
  const int bm = rem / nbn;
  const int bn = rem - bm * nbn;
  const int gm0 = bm * 256, gn0 = bn * 256;

  const unsigned short* Ag = A + (size_t)bz * sA;
  const unsigned short* Bg = B + (size_t)bz * sB;

  const int tid = threadIdx.x;
  const int w = tid >> 6, l = tid & 63;
  const int wr = w >> 2, wc = w & 3;
  const int lr = l & 15;
  const int lk16 = (l >> 4) * 16;
  const int swz = (lr & 7) << 4;

  const int srow0 = (tid * 16) >> 7;
  const int srow1 = srow0 + 64;
  const int sbo   = ((tid * 16) & 127) ^ ((srow0 & 7) << 4);
  const int sdst0 = tid * 16;
  const int sdst1 = tid * 16 + 8192;

#define STAGE(gbase, grow0, region, ktile)                                     \
  do {                                                                         \
    const char* _s0 =                                                          \
        (const char*)((gbase) + (size_t)((grow0) + srow0) * K) +               \
        (ktile) * 128 + sbo;                                                   \
    const char* _s1 =                                                          \
        (const char*)((gbase) + (size_t)((grow0) + srow1) * K) +               \
        (ktile) * 128 + sbo;                                                   \
    gload16(_s0, (region) + sdst0);                                            \
    gload16(_s1, (region) + sdst1);                                            \
  } while (0)

#define RDA(dst, m, kh) \
  dst = *(const bf16x8*)(Areg + ((m) * 16 + lr) * 128 + ((lk16 + (kh) * 64) ^ swz))
#define RDB(dst, n, kh) \
  dst = *(const bf16x8*)(Breg + (((wc & 1) * 64 + (n) * 16 + lr) * 128) + ((lk16 + (kh) * 64) ^ swz))

  f32x4 acc[8][4];
#pragma unroll
  for (int i = 0; i < 8; ++i)
#pragma unroll
    for (int j = 0; j < 4; ++j) acc[i][j] = (f32x4){0.f, 0.f, 0.f, 0.f};

  bf16x8 af[4][2], bf_[4][2];

#define MM(mi, ai, n)                                                          \
  acc[mi][n] = __builtin_amdgcn_mfma_f32_16x16x32_bf16(af[ai][0], bf_[n][0],   \
                                                       acc[mi][n], 0, 0, 0);   \
  acc[mi][n] = __builtin_amdgcn_mfma_f32_16x16x32_bf16(af[ai][1], bf_[n][1],   \
                                                       acc[mi][n], 0, 0, 0)

#define LGKM_PIN()                                          \
  asm volatile("s_waitcnt lgkmcnt(0)" ::: "memory");        \
  __builtin_amdgcn_sched_barrier(0)

  const int nt = K >> 6;

  STAGE(Bg, gn0,       ldsB + 0,     0);
  STAGE(Bg, gn0 + 128, ldsB + 16384, 0);
  STAGE(Ag, gm0,       ldsA + 0,     0);
  STAGE(Ag, gm0 + 128, ldsA + 16384, 0);
  STAGE(Bg, gn0,       ldsB + 32768,         1);
  STAGE(Bg, gn0 + 128, ldsB + 32768 + 16384, 1);
  STAGE(Ag, gm0,       ldsA + 32768,         1);
  asm volatile("s_waitcnt vmcnt(6)" ::: "memory");
  __builtin_amdgcn_s_barrier();

  for (int t = 0; t < nt; ++t) {
    const int cur = t & 1;
    char* Areg  = ldsA + cur * 32768 + wr * 16384;
    char* Breg  = ldsB + cur * 32768 + (wc >> 1) * 16384;
    char* Anext = ldsA + (cur ^ 1) * 32768;
    char* Acur2 = ldsA + cur * 32768;
    char* Bcur2 = ldsB + cur * 32768;

#pragma unroll
    for (int m = 0; m < 4; ++m) { RDA(af[m][0], m, 0); RDA(af[m][1], m, 1); }
#pragma unroll
    for (int n = 0; n < 2; ++n) { RDB(bf_[n][0], n, 0); RDB(bf_[n][1], n, 1); }
    if (wc < 2) {
#pragma unroll
      for (int n = 2; n < 4; ++n) { RDB(bf_[n][0], n, 0); RDB(bf_[n][1], n, 1); }
    }
    if (t + 1 < nt) STAGE(Ag, gm0 + 128, Anext + 16384, t + 1);
    __builtin_amdgcn_s_barrier();
    LGKM_PIN();
    __builtin_amdgcn_s_setprio(1);
    MM(0, 0, 0); MM(0, 0, 1); MM(1, 1, 0); MM(1, 1, 1);
    MM(2, 2, 0); MM(2, 2, 1); MM(3, 3, 0); MM(3, 3, 1);
    __builtin_amdgcn_s_setprio(0);
    __builtin_amdgcn_s_barrier();

    if (wc >= 2) {
#pragma unroll
      for (int n = 2; n < 4; ++n) { RDB(bf_[n][0], n, 0); RDB(bf_[n][1], n, 1); }
    }
    if (t + 2 < nt) STAGE(Bg, gn0, Bcur2, t + 2);
    __builtin_amdgcn_s_barrier();
    LGKM_PIN();
    __builtin_amdgcn_s_setprio(1);
    MM(0, 0, 2); MM(0, 0, 3); MM(1, 1, 2); MM(1, 1, 3);
    MM(2, 2, 2); MM(2, 2, 3); MM(3, 3, 2); MM(3, 3, 3);
    __builtin_amdgcn_s_setprio(0);
    __builtin_amdgcn_s_barrier();

#pragma unroll
    for (int m = 0; m < 4; ++m) { RDA(af[m][0], m + 4, 0); RDA(af[m][1], m + 4, 1); }
    if (t + 2 < nt) STAGE(Bg, gn0 + 128, Bcur2 + 16384, t + 2);
    __builtin_amdgcn_s_barrier();
    LGKM_PIN();
    __builtin_amdgcn_s_setprio(1);
    MM(4, 0, 0); MM(4, 0, 1); MM(5, 1, 0); MM(5, 1, 1);
    MM(6, 2, 0); MM(6, 2, 1); MM(7, 3, 0); MM(7, 3, 1);
    __builtin_amdgcn_s_setprio(0);
    __builtin_amdgcn_s_barrier();

    if (t + 2 < nt) STAGE(Ag, gm0, Acur2, t + 2);
    __builtin_amdgcn_s_barrier();
    __builtin_amdgcn_s_setprio(1);
    MM(4, 0, 2); MM(4, 0, 3); MM(5, 1, 2); MM(5, 1, 3);
    MM(6, 2, 2); MM(6, 2, 3); MM(7, 3, 2); MM(7, 3, 3);
    __builtin_amdgcn_s_setprio(0);
    if (t + 2 < nt) {
      asm volatile("s_waitcnt vmcnt(6)" ::: "memory");
    } else {
      asm volatile("s_waitcnt vmcnt(0)" ::: "memory");
    }
    __builtin_amdgcn_s_barrier();
  }

  // epilogue: E = 2^s' bf16 — raw v_exp_f32, pure convert+store
  const int cr = (l >> 4) * 4;
  const int cc = l & 15;
  unsigned short* Cp = C + (size_t)bz * sC;
#pragma unroll
  for (int m = 0; m < 8; ++m) {
    const int row = gm0 + wr * 128 + m * 16 + cr;
#pragma unroll
    for (int n = 0; n < 4; ++n) {
      const int col = gn0 + wc * 64 + n * 16 + cc;
      f32x4 a = acc[m][n];
#pragma unroll
      for (int j = 0; j < 4; ++j)
        Cp[(size_t)(row + j) * 2048 + col] =
            f2bf(__builtin_amdgcn_exp2f(a[j]));
    }
  }
#undef STAGE
#undef RDA
#undef RDB
#undef MM
#undef LGKM_PIN
}

extern "C" void kernel_launch(void* const* d_in, const int* in_sizes, int n_in,
                              void* d_out, int out_size, void* d_ws, size_t ws_size,
                              hipStream_t stream) {
  const float* x  = (const float*)d_in[0];
  const float* Wq = (const float*)d_in[1];
  const float* bq = (const float*)d_in[2];
  const float* Wk = (const float*)d_in[3];
  const float* bk = (const float*)d_in[4];  (void)bk;  // cancels in softmax
  const float* Wv = (const float*)d_in[5];
  const float* bv = (const float*)d_in[6];
  const float* Wp = (const float*)d_in[7];
  const float* bp = (const float*)d_in[8];
  float* out = (float*)d_out;

  char* ws = (char*)d_ws;
  unsigned short* x_bf  = (unsigned short*)(ws);
  unsigned short* Wp_bf = (unsigned short*)(ws + (16ull << 20));
  unsigned short* WqT   = (unsigned short*)(ws + (18ull << 20));
  unsigned short* WkT   = (unsigned short*)(ws + (20ull << 20));
  unsigned short* WvT   = (unsigned short*)(ws + (22ull << 20));
  unsigned short* HT    = (unsigned short*)(ws + (24ull << 20));
  unsigned short* G     = (unsigned short*)(ws + (26ull << 20));
  float*          c1    = (float*)(ws + (28ull << 20));
  float*          cv    = (float*)(ws + (28ull << 20) + 65536);
  unsigned short* R     = (unsigned short*)(ws + (32ull << 20));
  unsigned short* VWt   = (unsigned short*)(ws + (48ull << 20));
  unsigned short* Em    = (unsigned short*)(ws + (64ull << 20));

  // scale/ln2: exp2(s') == exp(s); fold propagates linearly through R
  const float scale_ht = 0.022097086912079608f * 1.4426950408889634f;

  prep1<<<1280, 256, 0, stream>>>(Wq, Wk, Wv, Wp, WqT, WkT, WvT, Wp_bf);
  prep2<<<256, 512, 0, stream>>>(WkT, WqT, Wp_bf, WvT, HT, G,
                                 x, x_bf, bq, Wk, Wp, bv, c1, cv, scale_ht);
  gmid<<<512, 512, 0, stream>>>(x_bf, HT, R, c1, G, VWt, cv);
  gsco8<<<256, 512, 0, stream>>>(R, x_bf, Em,
                                 1024, 2097152, 2097152, 4194304, 8, 8);
  gout<<<256, 512, 0, stream>>>(Em, VWt, out, bp);
}